// Round 1
// baseline (205.110 us; speedup 1.0000x reference)
//
#include <hip/hip_runtime.h>
#include <cstddef>
#include <cstdint>

// ---------------------------------------------------------------------------
// B=8, N=1024, C=768, H=12, hd=64.  All matmuls mfma_f32_16x16x32_bf16.
// R9: qkv_gemm rebuilt as 256x256-tile, 8-wave, BK=64, double-buffered LDS
// (128 KiB) with 4 phases/K-tile x 16 MFMA, counted vmcnt (10/8, never 0 in
// loop), raw s_barrier + lgkmcnt(0) (no vmcnt drain at barriers), setprio
// around MFMA clusters.  288 blocks (8 XCD x 36).  q/k epilogue: direct 8B
// packed stores (4 consecutive d per lane); v epilogue: 2-pass LDS scratch
// transpose reusing the stage buffers.  cvt kernels merged into one launch.
// attn_mfma / proj_gemm unchanged from R8.
// ---------------------------------------------------------------------------

typedef __attribute__((ext_vector_type(4))) float f32x4;
typedef __attribute__((ext_vector_type(8))) __bf16 bf16x8;
typedef __attribute__((ext_vector_type(4))) unsigned int uint4v;
typedef __attribute__((ext_vector_type(2))) unsigned int uint2v;

#define QK_PRESCALE 0.18033688011112042f   // 64^-0.5 * log2(e); softmax uses exp2

// round-half-up bf16: max error 0.5 ulp
__device__ __forceinline__ unsigned short f2bf(float f) {
  return (unsigned short)((__float_as_uint(f) + 0x8000u) >> 16);
}
// pack two floats -> bf16x2 in one v_perm_b32
__device__ __forceinline__ unsigned int pack2bf(float flo, float fhi) {
  unsigned ulo = __float_as_uint(flo) + 0x8000u;
  unsigned uhi = __float_as_uint(fhi) + 0x8000u;
  return __builtin_amdgcn_perm(uhi, ulo, 0x07060302);
}

// one wave instruction: 64 lanes x 16 B -> LDS[base + lane*16]
__device__ __forceinline__ void gl_lds16(const unsigned short* g, unsigned short* l) {
  __builtin_amdgcn_global_load_lds(
      (const __attribute__((address_space(1))) unsigned int*)g,
      (__attribute__((address_space(3))) unsigned int*)l, 16, 0, 0);
}

// ---------------------------------------------------------------------------
// fp32 -> bf16 conversion for x / qkv_w / proj_w in ONE launch.
// blocks: [0,6144) x (1572864 f4) | [6144,7872) qkv_w (442368) | rest proj_w.
// ---------------------------------------------------------------------------
__global__ __launch_bounds__(256)
void cvt3_kernel(const float* __restrict__ s0, unsigned short* __restrict__ d0,
                 const float* __restrict__ s1, unsigned short* __restrict__ d1,
                 const float* __restrict__ s2, unsigned short* __restrict__ d2) {
  int bid = blockIdx.x;
  const float* s; unsigned short* d; int i; int n4;
  if (bid < 6144)      { s = s0; d = d0; i = bid * 256 + threadIdx.x;            n4 = 1572864; }
  else if (bid < 7872) { s = s1; d = d1; i = (bid - 6144) * 256 + threadIdx.x;   n4 = 442368; }
  else                 { s = s2; d = d2; i = (bid - 7872) * 256 + threadIdx.x;   n4 = 147456; }
  if (i < n4) {
    float4 v = ((const float4*)s)[i];
    uint2v o;
    o.x = pack2bf(v.x, v.y);
    o.y = pack2bf(v.z, v.w);
    ((uint2v*)d)[i] = o;
  }
}

// ---------------------------------------------------------------------------
// QKV GEMM: A = wqkv (2304 feature rows), B = x (8192 token rows), K = 768.
// Tile: 256 features x 256 tokens, 8 waves (2 feat x 4 tok), per-wave 128x64.
// LDS: A[2][256][64] | B[2][256][64] = 128 KiB double buffer.
// Stage groups (per K-tile, each 128 rows = 2 gl_lds/wave):
//   Ga0 = feat rows {0-63, 128-191}   (read at phases q0,q1)
//   Ga1 = feat rows {64-127, 192-255} (read q2,q3)
//   Gb0 = tok rows  {wc*64+[0,32)}    (read q0,q2)
//   Gb1 = tok rows  {wc*64+[32,64)}   (read q1,q3)
// Phase (t,q): stage -> [vmcnt] -> s_barrier -> ds_read frags -> 16 MFMA
//              -> lgkmcnt(0) -> s_barrier.
// Stage schedule: (t,0):Ga1(t+1) (t,1):Gb1(t+1) (t,2):Ga0(t+2) (t,3):Gb0(t+2),
// clamped to tile 11 (idempotent duplicate loads keep vmcnt counts uniform).
// vmcnt(10) at q0 (guarantees Ga0/Gb0 of t), vmcnt(8) at q1 (Gb1 of t).
// ---------------------------------------------------------------------------
__global__ __launch_bounds__(512, 2)
void qkv_gemm(const unsigned short* __restrict__ xb, const unsigned short* __restrict__ wb,
              const float* __restrict__ qb, const float* __restrict__ vb,
              unsigned short* __restrict__ qo, unsigned short* __restrict__ ko,
              unsigned short* __restrict__ vto) {
  __shared__ __align__(16) unsigned short lds[65536];  // 128 KiB: A dbuf | B dbuf
  const int tid = threadIdx.x;
  const int lane = tid & 63, wid = tid >> 6;
  const int lm = lane & 15, lq = lane >> 4;
  const int xsw = lm & 7;
  const int wr = wid >> 2, wc = wid & 3;        // wave: feature-half, token-quarter
  const int L = blockIdx.x;
  const int xcd = L & 7, s = L >> 3;            // s: 0..35
  const int tt = xcd * 4 + s / 9;               // token tile 0..31
  const int ft = s % 9;                         // feature tile 0..8
  const int m0 = tt * 256;                      // token base
  const int n0 = ft * 256;                      // feature base
  const int srow = lane >> 3;                   // 0..7
  const int scolsw = ((lane & 7) ^ srow) * 8;   // swizzled source chunk
  const int laG = wr * 128 + wc * 16;           // A stage row base (per wave)
  const int lbG = (wid >> 1) * 64 + (wid & 1) * 16;  // B stage row base
  const unsigned short* pa = wb + (size_t)(n0 + laG + srow) * 768 + scolsw;
  const unsigned short* pb = xb + (size_t)(m0 + lbG + srow) * 768 + scolsw;

  f32x4 acc[8][4] = {};

#define STAGE_A(g, tgt) { \
    const unsigned short* _s = pa + (size_t)(g) * 64 * 768 + (size_t)(tgt) * 64; \
    unsigned short* _d = &lds[(((tgt) & 1) * 256 + laG + (g) * 64) * 64]; \
    gl_lds16(_s, _d); \
    gl_lds16(_s + (size_t)8 * 768, _d + 8 * 64); }

#define STAGE_B(g, tgt) { \
    const unsigned short* _s = pb + (size_t)(g) * 32 * 768 + (size_t)(tgt) * 64; \
    unsigned short* _d = &lds[32768 + (((tgt) & 1) * 256 + lbG + (g) * 32) * 64]; \
    gl_lds16(_s, _d); \
    gl_lds16(_s + (size_t)8 * 768, _d + 8 * 64); }

#define PHASE_COMPUTE(qA, qB, bufb) { \
    const unsigned short* _Ab = &lds[(bufb) * 16384]; \
    const unsigned short* _Bb = &lds[32768 + (bufb) * 16384]; \
    bf16x8 af[4][2], bff[2][2]; \
    _Pragma("unroll") for (int m2 = 0; m2 < 4; ++m2) \
      _Pragma("unroll") for (int kx = 0; kx < 2; ++kx) \
        af[m2][kx] = *(const bf16x8*)&_Ab[(wr * 128 + ((qA) * 4 + m2) * 16 + lm) * 64 + (((kx * 4 + lq) ^ xsw) * 8)]; \
    _Pragma("unroll") for (int n2 = 0; n2 < 2; ++n2) \
      _Pragma("unroll") for (int kx = 0; kx < 2; ++kx) \
        bff[n2][kx] = *(const bf16x8*)&_Bb[(wc * 64 + ((qB) * 2 + n2) * 16 + lm) * 64 + (((kx * 4 + lq) ^ xsw) * 8)]; \
    __builtin_amdgcn_s_setprio(1); \
    _Pragma("unroll") for (int kx = 0; kx < 2; ++kx) \
      _Pragma("unroll") for (int m2 = 0; m2 < 4; ++m2) \
        _Pragma("unroll") for (int n2 = 0; n2 < 2; ++n2) \
          acc[(qA) * 4 + m2][(qB) * 2 + n2] = __builtin_amdgcn_mfma_f32_16x16x32_bf16( \
              af[m2][kx], bff[n2][kx], acc[(qA) * 4 + m2][(qB) * 2 + n2], 0, 0, 0); \
    __builtin_amdgcn_s_setprio(0); }

#define BAR_A_VM10() asm volatile("s_waitcnt vmcnt(10)\ns_barrier" ::: "memory")
#define BAR_A_VM8()  asm volatile("s_waitcnt vmcnt(8)\ns_barrier" ::: "memory")
#define BAR_A()      asm volatile("s_barrier" ::: "memory")
#define BAR_B()      asm volatile("s_waitcnt lgkmcnt(0)\ns_barrier" ::: "memory")

  // prologue: t0 {Ga0,Gb0,Ga1,Gb1}, t1 {Ga0,Gb0}  (order matters for vmcnt math)
  STAGE_A(0, 0); STAGE_B(0, 0); STAGE_A(1, 0); STAGE_B(1, 0);
  STAGE_A(0, 1); STAGE_B(0, 1);

  for (int t = 0; t < 12; ++t) {
    const int b = t & 1;
    const int t1c = (t + 1 < 12) ? t + 1 : 11;
    const int t2c = (t + 2 < 12) ? t + 2 : 11;
    // q0: reads Ga0(t), Gb0(t)
    STAGE_A(1, t1c);
    BAR_A_VM10();
    PHASE_COMPUTE(0, 0, b);
    BAR_B();
    // q1: reads Ga0(t), Gb1(t)
    STAGE_B(1, t1c);
    BAR_A_VM8();
    PHASE_COMPUTE(0, 1, b);
    BAR_B();
    // q2: reads Ga1(t), Gb0(t)
    STAGE_A(0, t2c);
    BAR_A();
    PHASE_COMPUTE(1, 0, b);
    BAR_B();
    // q3: reads Ga1(t), Gb1(t)
    STAGE_B(0, t2c);
    BAR_A();
    PHASE_COMPUTE(1, 1, b);
    BAR_B();
  }
  asm volatile("s_waitcnt vmcnt(0)" ::: "memory");  // drain tail dup-stages

#undef STAGE_A
#undef STAGE_B
#undef PHASE_COMPUTE

  // ---------------- epilogue ----------------
  const int bq = tt >> 2;               // batch
  const int tokb = (tt & 3) * 256;      // token offset within batch
  if (ft < 6) {
    // q/k: acc rows = feature (lq*4+r within mi*16 group), cols = token (lm).
    // 4 consecutive d per lane -> direct packed 8B stores.
    const bool isq = ft < 3;
    unsigned short* dst0 = isq ? qo : ko;
    const int fbase = (isq ? ft : ft - 3) * 256 + wr * 128;
#pragma unroll
    for (int mi = 0; mi < 8; ++mi) {
      const int dg = fbase + mi * 16 + lq * 4;
      const int hh = dg >> 6;
      const int dih = dg & 63;
      f32x4 bias4 = {0.f, 0.f, 0.f, 0.f};
      if (isq) bias4 = *(const f32x4*)&qb[ft * 256 + wr * 128 + mi * 16 + lq * 4];
#pragma unroll
      for (int ni = 0; ni < 4; ++ni) {
        const int tok = tokb + wc * 64 + ni * 16 + lm;
        uint2v pk;
        if (isq) {
          pk.x = pack2bf((acc[mi][ni][0] + bias4[0]) * QK_PRESCALE,
                         (acc[mi][ni][1] + bias4[1]) * QK_PRESCALE);
          pk.y = pack2bf((acc[mi][ni][2] + bias4[2]) * QK_PRESCALE,
                         (acc[mi][ni][3] + bias4[3]) * QK_PRESCALE);
        } else {
          pk.x = pack2bf(acc[mi][ni][0], acc[mi][ni][1]);
          pk.y = pack2bf(acc[mi][ni][2], acc[mi][ni][3]);
        }
        *(uint2v*)&dst0[(((size_t)(bq * 12 + hh)) * 1024 + tok) * 64 + dih] = pk;
      }
    }
  } else {
    // v: need vto[(bh*64+d)*1024 + tok].  Transpose via LDS scratch (stride 264),
    // two passes over the feature halves (wr==p waves own features p*128+[0,128)).
    const int vb0 = (ft - 6) * 256;
    unsigned short* scr = lds;
#pragma unroll
    for (int p = 0; p < 2; ++p) {
      __syncthreads();                 // also fully drains per-wave vmcnt
      if (wr == p) {
#pragma unroll
        for (int mi = 0; mi < 8; ++mi) {
          f32x4 bias4 = *(const f32x4*)&vb[vb0 + p * 128 + mi * 16 + lq * 4];
#pragma unroll
          for (int ni = 0; ni < 4; ++ni) {
            const int tok = wc * 64 + ni * 16 + lm;
#pragma unroll
            for (int r = 0; r < 4; ++r)
              scr[(mi * 16 + lq * 4 + r) * 264 + tok] = f2bf(acc[mi][ni][r] + bias4[r]);
          }
        }
      }
      __syncthreads();
      {
        const int row = tid >> 2, tq = tid & 3;
        const int dgv = vb0 + p * 128 + row;
        const int hh = dgv >> 6, d = dgv & 63;
        unsigned short* dstv = vto + (((size_t)(bq * 12 + hh)) * 64 + d) * 1024 + tokb + tq * 64;
        const unsigned short* srcr = &scr[row * 264 + tq * 64];
#pragma unroll
        for (int j = 0; j < 8; ++j)
          *(uint4v*)&dstv[j * 8] = *(const uint4v*)&srcr[j * 8];
      }
    }
  }
}

// ---------------------------------------------------------------------------
// Flash attention. 768 blocks = 8 XCD x (12 bh x 8 q-tiles).  (unchanged R8)
// ---------------------------------------------------------------------------
__global__ __launch_bounds__(256)
void attn_mfma(const unsigned short* __restrict__ q, const unsigned short* __restrict__ k,
               const unsigned short* __restrict__ vt, const int* __restrict__ mask,
               unsigned short* __restrict__ ao) {
  __shared__ unsigned short ks_s[64 * 64];     // [key][hd], swizzled chunks
  __shared__ unsigned short vs_s[64 * 64];     // [hd][key], swizzled chunks
  __shared__ unsigned short ps[4][32 * 72];    // per-wave P [q][key], stride 72
  __shared__ float mkl[64];
  const int tid = threadIdx.x;
  const int lane = tid & 63, wid = tid >> 6;
  const int lm = lane & 15, lq = lane >> 4;
  const int xsw = lm & 7;
  const int L = blockIdx.x;
  const int xcd = L & 7, s = L >> 3;           // s: 0..95
  const int bh = xcd * 12 + s / 8;
  const int qt = s % 8;
  const int bb = bh / 12, hh = bh % 12;
  const unsigned short* qp = q + (size_t)bh * 65536;
  const unsigned short* kp = k + (size_t)bh * 65536;
  const unsigned short* vp = vt + (size_t)bh * 65536;
  const int* mp = mask + bb * 1024;
  const int q0 = qt * 128 + wid * 32;
  const int srow = lane >> 3;
  const int scolsw = ((lane & 7) ^ srow) * 8;
  const unsigned short* gk = kp + (size_t)(wid * 16 + srow) * 64 + scolsw;
  const unsigned short* gv = vp + (size_t)(wid * 16 + srow) * 1024 + scolsw;

  bf16x8 qf[2][2];
#pragma unroll
  for (int mi = 0; mi < 2; ++mi)
#pragma unroll
    for (int ks2 = 0; ks2 < 2; ++ks2)
      qf[mi][ks2] = *(const bf16x8*)&qp[(size_t)(q0 + mi * 16 + lm) * 64 + ks2 * 32 + lq * 8];
  bf16x8 ones;
#pragma unroll
  for (int i = 0; i < 8; ++i) ones[i] = (__bf16)1.0f;

  f32x4 o_acc[2][4] = {};
  f32x4 l_acc[2] = {};

  for (int kt = 0; kt < 16; ++kt) {
    __syncthreads();                           // drain prior tile reads
#pragma unroll
    for (int i = 0; i < 2; ++i) {
      gl_lds16(gk + (size_t)kt * 4096 + (size_t)i * 8 * 64, &ks_s[(wid * 16 + i * 8) * 64]);
      gl_lds16(gv + (size_t)kt * 64 + (size_t)i * 8 * 1024, &vs_s[(wid * 16 + i * 8) * 64]);
    }
    if (tid < 64) mkl[tid] = mp[kt * 64 + tid] ? -1e30f : 0.0f;
    __syncthreads();

    // S^T = K Q^T : tile [key-tile nt][q-tile mi]; col=q=lm, row=key=lq*4+r
    f32x4 st[4][2] = {};
#pragma unroll
    for (int ks2 = 0; ks2 < 2; ++ks2) {
      bf16x8 kf[4];
#pragma unroll
      for (int nt = 0; nt < 4; ++nt)
        kf[nt] = *(const bf16x8*)&ks_s[(nt * 16 + lm) * 64 + (((ks2 * 4 + lq) ^ xsw) * 8)];
#pragma unroll
      for (int nt = 0; nt < 4; ++nt)
#pragma unroll
        for (int mi = 0; mi < 2; ++mi)
          st[nt][mi] = __builtin_amdgcn_mfma_f32_16x16x32_bf16(kf[nt], qf[mi][ks2], st[nt][mi], 0, 0, 0);
    }

    // p = exp2(st + mask[key]) via raw v_exp_f32; packed b64 P writes
#pragma unroll
    for (int nt = 0; nt < 4; ++nt) {
      f32x4 mv4 = *(const f32x4*)&mkl[nt * 16 + lq * 4];
#pragma unroll
      for (int mi = 0; mi < 2; ++mi) {
        uint2v pk;
        pk.x = pack2bf(__builtin_amdgcn_exp2f(st[nt][mi][0] + mv4[0]),
                       __builtin_amdgcn_exp2f(st[nt][mi][1] + mv4[1]));
        pk.y = pack2bf(__builtin_amdgcn_exp2f(st[nt][mi][2] + mv4[2]),
                       __builtin_amdgcn_exp2f(st[nt][mi][3] + mv4[3]));
        *(uint2v*)&ps[wid][(mi * 16 + lm) * 72 + nt * 16 + lq * 4] = pk;
      }
    }

    // O += P V ; l += P . 1   (ps wave-private: no barrier)
#pragma unroll
    for (int ks2 = 0; ks2 < 2; ++ks2) {
      bf16x8 pf[2], vf[4];
#pragma unroll
      for (int mi = 0; mi < 2; ++mi)
        pf[mi] = *(const bf16x8*)&ps[wid][(mi * 16 + lm) * 72 + ks2 * 32 + lq * 8];
#pragma unroll
      for (int nt = 0; nt < 4; ++nt)
        vf[nt] = *(const bf16x8*)&vs_s[(nt * 16 + lm) * 64 + (((ks2 * 4 + lq) ^ xsw) * 8)];
#pragma unroll
      for (int mi = 0; mi < 2; ++mi) {
#pragma unroll
        for (int nt = 0; nt < 4; ++nt)
          o_acc[mi][nt] = __builtin_amdgcn_mfma_f32_16x16x32_bf16(pf[mi], vf[nt], o_acc[mi][nt], 0, 0, 0);
        l_acc[mi] = __builtin_amdgcn_mfma_f32_16x16x32_bf16(pf[mi], ones, l_acc[mi], 0, 0, 0);
      }
    }
  }

  // epilogue: ao[b, tok, h*64+d] = O/l  (bf16)
#pragma unroll
  for (int mi = 0; mi < 2; ++mi) {
#pragma unroll
    for (int r = 0; r < 4; ++r) {
      float inv = 1.0f / l_acc[mi][r];
      int tok = q0 + mi * 16 + lq * 4 + r;
#pragma unroll
      for (int nt = 0; nt < 4; ++nt)
        ao[(size_t)(bb * 1024 + tok) * 768 + hh * 64 + nt * 16 + lm] = f2bf(o_acc[mi][nt][r] * inv);
    }
  }
}

// ---------------------------------------------------------------------------
// Proj GEMM: M=8192, N=768, K=768.  (unchanged R8)
// ---------------------------------------------------------------------------
__global__ __launch_bounds__(256)
void proj_gemm(const unsigned short* __restrict__ ab, const unsigned short* __restrict__ wb,
               const float* __restrict__ pb, float* __restrict__ out) {
  __shared__ unsigned short as[128 * 64];   // w rows
  __shared__ unsigned short bs[128 * 64];   // ao rows
  const int tid = threadIdx.x;
  const int lane = tid & 63, wid = tid >> 6;
  const int lm = lane & 15, lq = lane >> 4;
  const int xsw = lm & 7;
  const int wm = (wid & 1) * 64, wn = (wid >> 1) * 64;
  const int L = blockIdx.x;
  const int xcd = L & 7, s = L >> 3;           // s: 0..47
  const int m0 = (xcd * 8 + s / 6) * 128;
  const int n0 = (s % 6) * 128;
  const int srow = lane >> 3;
  const int scolsw = ((lane & 7) ^ srow) * 8;
  const unsigned short* ga = wb + (size_t)(n0 + wid * 32 + srow) * 768 + scolsw;
  const unsigned short* gb = ab + (size_t)(m0 + wid * 32 + srow) * 768 + scolsw;
  f32x4 acc[4][4] = {};
  for (int kt = 0; kt < 768; kt += 64) {
#pragma unroll
    for (int i = 0; i < 4; ++i) {
      gl_lds16(ga + kt + (size_t)i * 8 * 768, &as[(wid * 32 + i * 8) * 64]);
      gl_lds16(gb + kt + (size_t)i * 8 * 768, &bs[(wid * 32 + i * 8) * 64]);
    }
    __syncthreads();
#pragma unroll
    for (int ks = 0; ks < 2; ++ks) {
      bf16x8 af[4], bf[4];
#pragma unroll
      for (int i = 0; i < 4; ++i)
        af[i] = *(const bf16x8*)&as[(wm + i * 16 + lm) * 64 + (((ks * 4 + lq) ^ xsw) * 8)];
#pragma unroll
      for (int i = 0; i < 4; ++i)
        bf[i] = *(const bf16x8*)&bs[(wn + i * 16 + lm) * 64 + (((ks * 4 + lq) ^ xsw) * 8)];
#pragma unroll
      for (int mi = 0; mi < 4; ++mi)
#pragma unroll
        for (int ni = 0; ni < 4; ++ni)
          acc[mi][ni] = __builtin_amdgcn_mfma_f32_16x16x32_bf16(af[mi], bf[ni], acc[mi][ni], 0, 0, 0);
    }
    __syncthreads();
  }
  // acc rows = n-dim, cols = m-dim
#pragma unroll
  for (int mi = 0; mi < 4; ++mi) {
    int gn0 = n0 + wm + mi * 16 + lq * 4;
    f32x4 bias4 = *(const f32x4*)&pb[gn0];
#pragma unroll
    for (int ni = 0; ni < 4; ++ni) {
      int gm = m0 + wn + ni * 16 + lm;
      f32x4 o;
      o[0] = acc[mi][ni][0] + bias4[0];
      o[1] = acc[mi][ni][1] + bias4[1];
      o[2] = acc[mi][ni][2] + bias4[2];
      o[3] = acc[mi][ni][3] + bias4[3];
      *(f32x4*)&out[(size_t)gm * 768 + gn0] = o;
    }
  }
}

// ---------------------------------------------------------------------------
// ws layout (bf16 elts): xb 6291456 | wqkv 1769472 | wproj 589824 |
//   q 6291456 | k 6291456 | v^T 6291456 | ao 6291456   (~67.6 MB)
// ---------------------------------------------------------------------------
extern "C" void kernel_launch(void* const* d_in, const int* in_sizes, int n_in,
                              void* d_out, int out_size, void* d_ws, size_t ws_size,
                              hipStream_t stream) {
  const float* x      = (const float*)d_in[0];
  const int*   mask   = (const int*)d_in[1];
  const float* qkv_w  = (const float*)d_in[2];
  const float* q_bias = (const float*)d_in[3];
  const float* v_bias = (const float*)d_in[4];
  const float* proj_w = (const float*)d_in[5];
  const float* proj_b = (const float*)d_in[6];
  float* out = (float*)d_out;
  unsigned short* p = (unsigned short*)d_ws;
  unsigned short* xb     = p;              p += 6291456;
  unsigned short* wqkvb  = p;              p += 1769472;
  unsigned short* wprojb = p;              p += 589824;
  unsigned short* qo     = p;              p += 6291456;
  unsigned short* ko     = p;              p += 6291456;
  unsigned short* vto    = p;              p += 6291456;
  unsigned short* ao     = p;

  cvt3_kernel<<<8448, 256, 0, stream>>>(x, xb, qkv_w, wqkvb, proj_w, wprojb);
  qkv_gemm<<<288, 512, 0, stream>>>(xb, wqkvb, q_bias, v_bias, qo, ko, vto);
  attn_mfma<<<768, 256, 0, stream>>>(qo, ko, vto, mask, ao);
  proj_gemm<<<384, 256, 0, stream>>>(ao, wprojb, proj_b, out);
}

// Round 2
// 184.347 us; speedup vs baseline: 1.1126x; 1.1126x over previous
//
#include <hip/hip_runtime.h>
#include <cstddef>
#include <cstdint>

// ---------------------------------------------------------------------------
// B=8, N=1024, C=768, H=12, hd=64.  All matmuls mfma_f32_16x16x32_bf16.
// R10: qkv_gemm re-tiled 288feat x 256tok -> 8 x 32 = EXACTLY 256 blocks
// (one balanced round, no 2nd-round tail that cost R9 ~50%).  8 waves
// (2 feat-halves x 4 tok-quarters), per-wave 144x64 = 9x4 MFMA blocks.
// LDS 136 KiB double-buffered; 4-phase counted-vmcnt schedule (depth-1
// prefetch, per-wave vmcnt a0+4 / a0+2, never 0 in loop), setprio around
// MFMA clusters.  Epilogue: q/k direct packed stores per 16-feature
// rowblock; v via 2-pass 144x264 LDS scratch transpose.
// attn_mfma / proj_gemm / cvt3 unchanged from R9.
// ---------------------------------------------------------------------------

typedef __attribute__((ext_vector_type(4))) float f32x4;
typedef __attribute__((ext_vector_type(8))) __bf16 bf16x8;
typedef __attribute__((ext_vector_type(4))) unsigned int uint4v;
typedef __attribute__((ext_vector_type(2))) unsigned int uint2v;

#define QK_PRESCALE 0.18033688011112042f   // 64^-0.5 * log2(e); softmax uses exp2

// round-half-up bf16: max error 0.5 ulp
__device__ __forceinline__ unsigned short f2bf(float f) {
  return (unsigned short)((__float_as_uint(f) + 0x8000u) >> 16);
}
// pack two floats -> bf16x2 in one v_perm_b32
__device__ __forceinline__ unsigned int pack2bf(float flo, float fhi) {
  unsigned ulo = __float_as_uint(flo) + 0x8000u;
  unsigned uhi = __float_as_uint(fhi) + 0x8000u;
  return __builtin_amdgcn_perm(uhi, ulo, 0x07060302);
}

// one wave instruction: 64 lanes x 16 B -> LDS[base + lane*16]
__device__ __forceinline__ void gl_lds16(const unsigned short* g, unsigned short* l) {
  __builtin_amdgcn_global_load_lds(
      (const __attribute__((address_space(1))) unsigned int*)g,
      (__attribute__((address_space(3))) unsigned int*)l, 16, 0, 0);
}

// ---------------------------------------------------------------------------
// fp32 -> bf16 conversion for x / qkv_w / proj_w in ONE launch.
// ---------------------------------------------------------------------------
__global__ __launch_bounds__(256)
void cvt3_kernel(const float* __restrict__ s0, unsigned short* __restrict__ d0,
                 const float* __restrict__ s1, unsigned short* __restrict__ d1,
                 const float* __restrict__ s2, unsigned short* __restrict__ d2) {
  int bid = blockIdx.x;
  const float* s; unsigned short* d; int i; int n4;
  if (bid < 6144)      { s = s0; d = d0; i = bid * 256 + threadIdx.x;            n4 = 1572864; }
  else if (bid < 7872) { s = s1; d = d1; i = (bid - 6144) * 256 + threadIdx.x;   n4 = 442368; }
  else                 { s = s2; d = d2; i = (bid - 7872) * 256 + threadIdx.x;   n4 = 147456; }
  if (i < n4) {
    float4 v = ((const float4*)s)[i];
    uint2v o;
    o.x = pack2bf(v.x, v.y);
    o.y = pack2bf(v.z, v.w);
    ((uint2v*)d)[i] = o;
  }
}

// staging row tables (wave-uniform).  A tile = 288 rows; 8-row chunks.
// Ga0 = rows [0,80) u [144,224)  (20 ops): read at phases q0,q1
// Ga1 = rows [80,144) u [224,288) (16 ops): read q2,q3
__device__ __forceinline__ int a0row(int o) { return (o < 10) ? o * 8 : 144 + (o - 10) * 8; }
__device__ __forceinline__ int a1row(int o) { return (o < 8) ? 80 + o * 8 : 224 + (o - 8) * 8; }

// ---------------------------------------------------------------------------
// QKV GEMM: A = wqkv (2304 feature rows), B = x (8192 token rows), K = 768.
// Tile: 288 feat x 256 tok, 8 waves (wr=feat-half of 144, wc=tok-quarter of 64).
// LDS shorts: A dbuf [0, 36864) (2 x 288 x 64) | B dbuf [36864, 69632).
// Phases per K-tile t (each: stage -> [wait] -> s_barrier -> ds_read frags ->
// MFMA -> lgkmcnt(0) -> s_barrier):
//   q0: stage Ga0(t+1); wait vmcnt(a0n+4); compute rows 0-4 x cols 0-1  (20 MFMA)
//   q1: stage Gb0(t+1); wait vmcnt(a0n+2); compute rows 0-4 x cols 2-3
//   q2: stage Ga1(t+1); compute rows 5-8 x cols 0-1                     (16 MFMA)
//   q3: stage Gb1(t+1); compute rows 5-8 x cols 2-3
// Per-wave op counts: a0n = 3 (waves 0-3) or 2 (waves 4-7); b0/a1/b1 = 2 each.
// Tail t=11 stages duplicate (identical-data) loads -> benign race.
// ---------------------------------------------------------------------------
__global__ __launch_bounds__(512, 2)
void qkv_gemm(const unsigned short* __restrict__ xb, const unsigned short* __restrict__ wb,
              const float* __restrict__ qb, const float* __restrict__ vb,
              unsigned short* __restrict__ qo, unsigned short* __restrict__ ko,
              unsigned short* __restrict__ vto) {
  __shared__ __align__(16) unsigned short lds[69632];  // 136 KiB
  const int tid = threadIdx.x;
  const int lane = tid & 63, wid = tid >> 6;
  const int widu = __builtin_amdgcn_readfirstlane(wid);
  const int lm = lane & 15, lq = lane >> 4;
  const int xsw = lm & 7;
  const int wr = widu >> 2, wc = widu & 3;      // feat-half, tok-quarter
  const int L = blockIdx.x;
  const int xcd = L & 7, s = L >> 3;            // s: 0..31
  const int tt = xcd * 4 + (s >> 3);            // token tile 0..31
  const int ft = s & 7;                         // feature tile 0..7
  const int m0 = tt * 256;                      // token base
  const int n0 = ft * 288;                      // feature base
  const int srow = lane >> 3;                   // 0..7
  const int scolsw = ((lane & 7) ^ srow) * 8;   // pre-swizzled source chunk
  const unsigned short* paS = wb + (size_t)(n0 + srow) * 768 + scolsw;
  const unsigned short* pbS = xb + (size_t)(m0 + srow) * 768 + scolsw;

  // per-wave stage rows (SGPR via widu)
  const int a0n3 = (widu < 4);
  const int a0o = a0n3 ? widu * 3 : 12 + (widu - 4) * 2;
  const int a0r0 = a0row(a0o), a0r1 = a0row(a0o + 1);
  const int a0r2 = a0n3 ? a0row(a0o + 2) : 0;
  const int a1r0 = a1row(2 * widu), a1r1 = a1row(2 * widu + 1);
  const int b0q0 = (2 * widu) >> 2, b0q1 = (2 * widu + 1) >> 2;
  const int b0r0 = b0q0 * 64 + ((2 * widu) & 3) * 8;
  const int b0r1 = b0q1 * 64 + ((2 * widu + 1) & 3) * 8;
  const int b1r0 = b0r0 + 32, b1r1 = b0r1 + 32;

  f32x4 acc[9][4] = {};

#define STAGE_A0(tgt) { const size_t _c = (size_t)(tgt) * 64; const int _b = ((tgt) & 1) * 18432; \
    gl_lds16(paS + (size_t)a0r0 * 768 + _c, &lds[_b + a0r0 * 64]); \
    gl_lds16(paS + (size_t)a0r1 * 768 + _c, &lds[_b + a0r1 * 64]); \
    if (a0n3) gl_lds16(paS + (size_t)a0r2 * 768 + _c, &lds[_b + a0r2 * 64]); }

#define STAGE_A1(tgt) { const size_t _c = (size_t)(tgt) * 64; const int _b = ((tgt) & 1) * 18432; \
    gl_lds16(paS + (size_t)a1r0 * 768 + _c, &lds[_b + a1r0 * 64]); \
    gl_lds16(paS + (size_t)a1r1 * 768 + _c, &lds[_b + a1r1 * 64]); }

#define STAGE_B0(tgt) { const size_t _c = (size_t)(tgt) * 64; const int _b = 36864 + ((tgt) & 1) * 16384; \
    gl_lds16(pbS + (size_t)b0r0 * 768 + _c, &lds[_b + b0r0 * 64]); \
    gl_lds16(pbS + (size_t)b0r1 * 768 + _c, &lds[_b + b0r1 * 64]); }

#define STAGE_B1(tgt) { const size_t _c = (size_t)(tgt) * 64; const int _b = 36864 + ((tgt) & 1) * 16384; \
    gl_lds16(pbS + (size_t)b1r0 * 768 + _c, &lds[_b + b1r0 * 64]); \
    gl_lds16(pbS + (size_t)b1r1 * 768 + _c, &lds[_b + b1r1 * 64]); }

#define PHASE_COMPUTE(R0, NR, CB, bufb) { \
    const unsigned short* _Ab = &lds[(bufb) * 18432]; \
    const unsigned short* _Bb = &lds[36864 + (bufb) * 16384]; \
    bf16x8 af[NR][2], bff[2][2]; \
    _Pragma("unroll") for (int m2 = 0; m2 < (NR); ++m2) \
      _Pragma("unroll") for (int kx = 0; kx < 2; ++kx) \
        af[m2][kx] = *(const bf16x8*)&_Ab[(wr * 144 + ((R0) + m2) * 16 + lm) * 64 + (((kx * 4 + lq) ^ xsw) * 8)]; \
    _Pragma("unroll") for (int n2 = 0; n2 < 2; ++n2) \
      _Pragma("unroll") for (int kx = 0; kx < 2; ++kx) \
        bff[n2][kx] = *(const bf16x8*)&_Bb[(wc * 64 + ((CB) * 2 + n2) * 16 + lm) * 64 + (((kx * 4 + lq) ^ xsw) * 8)]; \
    __builtin_amdgcn_s_setprio(1); \
    _Pragma("unroll") for (int kx = 0; kx < 2; ++kx) \
      _Pragma("unroll") for (int m2 = 0; m2 < (NR); ++m2) \
        _Pragma("unroll") for (int n2 = 0; n2 < 2; ++n2) \
          acc[(R0) + m2][(CB) * 2 + n2] = __builtin_amdgcn_mfma_f32_16x16x32_bf16( \
              af[m2][kx], bff[n2][kx], acc[(R0) + m2][(CB) * 2 + n2], 0, 0, 0); \
    __builtin_amdgcn_s_setprio(0); }

#define WAIT_Q0() { if (a0n3) asm volatile("s_waitcnt vmcnt(7)" ::: "memory"); \
                    else      asm volatile("s_waitcnt vmcnt(6)" ::: "memory"); \
                    asm volatile("s_barrier" ::: "memory"); }
#define WAIT_Q1() { if (a0n3) asm volatile("s_waitcnt vmcnt(5)" ::: "memory"); \
                    else      asm volatile("s_waitcnt vmcnt(4)" ::: "memory"); \
                    asm volatile("s_barrier" ::: "memory"); }
#define BAR_A()   asm volatile("s_barrier" ::: "memory")
#define BAR_B()   asm volatile("s_waitcnt lgkmcnt(0)\ns_barrier" ::: "memory")

  // prologue: tile 0, issue order A0,B0,A1,B1 (FIFO order matters for vmcnt)
  STAGE_A0(0); STAGE_B0(0); STAGE_A1(0); STAGE_B1(0);

  for (int t = 0; t < 12; ++t) {
    const int b = t & 1;
    const int tn = (t < 11) ? t + 1 : 11;   // tail: idempotent dup stages
    // q0: reads Ga0(t), Gb0(t)
    STAGE_A0(tn);
    WAIT_Q0();
    PHASE_COMPUTE(0, 5, 0, b);
    BAR_B();
    // q1: reads Ga0(t), Gb1(t)
    STAGE_B0(tn);
    WAIT_Q1();
    PHASE_COMPUTE(0, 5, 1, b);
    BAR_B();
    // q2: reads Ga1(t), Gb0(t)   (all of tile t drained by q1's wait)
    STAGE_A1(tn);
    BAR_A();
    PHASE_COMPUTE(5, 4, 0, b);
    BAR_B();
    // q3: reads Ga1(t), Gb1(t)
    STAGE_B1(tn);
    BAR_A();
    PHASE_COMPUTE(5, 4, 1, b);
    BAR_B();
  }
  asm volatile("s_waitcnt vmcnt(0)" ::: "memory");  // drain tail dup-stages

#undef STAGE_A0
#undef STAGE_A1
#undef STAGE_B0
#undef STAGE_B1
#undef PHASE_COMPUTE

  // ---------------- epilogue ----------------
  const int bq = tt >> 2;               // batch
  const int tokb = (tt & 3) * 256;      // token offset within batch
  // q/k rowblocks: direct packed 8B stores (4 consecutive d per lane)
#pragma unroll
  for (int mi = 0; mi < 9; ++mi) {
    const int fblk = n0 + wr * 144 + mi * 16;   // 16-aligned; q/k/v boundary safe
    if (fblk < 1536) {
      const bool isq = fblk < 768;
      unsigned short* dst0 = isq ? qo : ko;
      const int fd = fblk - (isq ? 0 : 768);
      const int hh = fd >> 6;
      const int dih = (fd & 63) + lq * 4;
      f32x4 bias4 = {0.f, 0.f, 0.f, 0.f};
      if (isq) bias4 = *(const f32x4*)&qb[fblk + lq * 4];
#pragma unroll
      for (int ni = 0; ni < 4; ++ni) {
        const int tok = tokb + wc * 64 + ni * 16 + lm;
        uint2v pk;
        if (isq) {
          pk.x = pack2bf((acc[mi][ni][0] + bias4[0]) * QK_PRESCALE,
                         (acc[mi][ni][1] + bias4[1]) * QK_PRESCALE);
          pk.y = pack2bf((acc[mi][ni][2] + bias4[2]) * QK_PRESCALE,
                         (acc[mi][ni][3] + bias4[3]) * QK_PRESCALE);
        } else {
          pk.x = pack2bf(acc[mi][ni][0], acc[mi][ni][1]);
          pk.y = pack2bf(acc[mi][ni][2], acc[mi][ni][3]);
        }
        *(uint2v*)&dst0[(((size_t)(bq * 12 + hh)) * 1024 + tok) * 64 + dih] = pk;
      }
    }
  }
  // v rowblocks: transpose via LDS scratch (144 x stride 264), 2 passes
  if (n0 + 288 > 1536) {
#pragma unroll
    for (int p = 0; p < 2; ++p) {
      __syncthreads();
      if (wr == p) {
#pragma unroll
        for (int mi = 0; mi < 9; ++mi) {
          const int fblk = n0 + p * 144 + mi * 16;
          if (fblk >= 1536) {
            f32x4 bias4 = *(const f32x4*)&vb[fblk - 1536 + lq * 4];
#pragma unroll
            for (int ni = 0; ni < 4; ++ni) {
              const int tokl = wc * 64 + ni * 16 + lm;
#pragma unroll
              for (int r = 0; r < 4; ++r)
                lds[(mi * 16 + lq * 4 + r) * 264 + tokl] = f2bf(acc[mi][ni][r] + bias4[r]);
            }
          }
        }
      }
      __syncthreads();
      const int fv = 1536 - (n0 + p * 144);
      const int rv0 = fv > 0 ? fv : 0;
      for (int r = rv0 + (tid >> 2); r < 144; r += 128) {
        const int tq = tid & 3;
        const int dgv = n0 + p * 144 + r - 1536;      // 0..767
        const int hh = dgv >> 6, d = dgv & 63;
        unsigned short* dstv = vto + (((size_t)(bq * 12 + hh)) * 64 + d) * 1024 + tokb + tq * 64;
        const unsigned short* srcr = &lds[r * 264 + tq * 64];
#pragma unroll
        for (int j = 0; j < 8; ++j)
          *(uint4v*)&dstv[j * 8] = *(const uint4v*)&srcr[j * 8];
      }
    }
  }
}

// ---------------------------------------------------------------------------
// Flash attention. 768 blocks = 8 XCD x (12 bh x 8 q-tiles).  (unchanged)
// ---------------------------------------------------------------------------
__global__ __launch_bounds__(256)
void attn_mfma(const unsigned short* __restrict__ q, const unsigned short* __restrict__ k,
               const unsigned short* __restrict__ vt, const int* __restrict__ mask,
               unsigned short* __restrict__ ao) {
  __shared__ unsigned short ks_s[64 * 64];     // [key][hd], swizzled chunks
  __shared__ unsigned short vs_s[64 * 64];     // [hd][key], swizzled chunks
  __shared__ unsigned short ps[4][32 * 72];    // per-wave P [q][key], stride 72
  __shared__ float mkl[64];
  const int tid = threadIdx.x;
  const int lane = tid & 63, wid = tid >> 6;
  const int lm = lane & 15, lq = lane >> 4;
  const int xsw = lm & 7;
  const int L = blockIdx.x;
  const int xcd = L & 7, s = L >> 3;           // s: 0..95
  const int bh = xcd * 12 + s / 8;
  const int qt = s % 8;
  const int bb = bh / 12, hh = bh % 12;
  const unsigned short* qp = q + (size_t)bh * 65536;
  const unsigned short* kp = k + (size_t)bh * 65536;
  const unsigned short* vp = vt + (size_t)bh * 65536;
  const int* mp = mask + bb * 1024;
  const int q0 = qt * 128 + wid * 32;
  const int srow = lane >> 3;
  const int scolsw = ((lane & 7) ^ srow) * 8;
  const unsigned short* gk = kp + (size_t)(wid * 16 + srow) * 64 + scolsw;
  const unsigned short* gv = vp + (size_t)(wid * 16 + srow) * 1024 + scolsw;

  bf16x8 qf[2][2];
#pragma unroll
  for (int mi = 0; mi < 2; ++mi)
#pragma unroll
    for (int ks2 = 0; ks2 < 2; ++ks2)
      qf[mi][ks2] = *(const bf16x8*)&qp[(size_t)(q0 + mi * 16 + lm) * 64 + ks2 * 32 + lq * 8];
  bf16x8 ones;
#pragma unroll
  for (int i = 0; i < 8; ++i) ones[i] = (__bf16)1.0f;

  f32x4 o_acc[2][4] = {};
  f32x4 l_acc[2] = {};

  for (int kt = 0; kt < 16; ++kt) {
    __syncthreads();                           // drain prior tile reads
#pragma unroll
    for (int i = 0; i < 2; ++i) {
      gl_lds16(gk + (size_t)kt * 4096 + (size_t)i * 8 * 64, &ks_s[(wid * 16 + i * 8) * 64]);
      gl_lds16(gv + (size_t)kt * 64 + (size_t)i * 8 * 1024, &vs_s[(wid * 16 + i * 8) * 64]);
    }
    if (tid < 64) mkl[tid] = mp[kt * 64 + tid] ? -1e30f : 0.0f;
    __syncthreads();

    // S^T = K Q^T : tile [key-tile nt][q-tile mi]; col=q=lm, row=key=lq*4+r
    f32x4 st[4][2] = {};
#pragma unroll
    for (int ks2 = 0; ks2 < 2; ++ks2) {
      bf16x8 kf[4];
#pragma unroll
      for (int nt = 0; nt < 4; ++nt)
        kf[nt] = *(const bf16x8*)&ks_s[(nt * 16 + lm) * 64 + (((ks2 * 4 + lq) ^ xsw) * 8)];
#pragma unroll
      for (int nt = 0; nt < 4; ++nt)
#pragma unroll
        for (int mi = 0; mi < 2; ++mi)
          st[nt][mi] = __builtin_amdgcn_mfma_f32_16x16x32_bf16(kf[nt], qf[mi][ks2], st[nt][mi], 0, 0, 0);
    }

    // p = exp2(st + mask[key]) via raw v_exp_f32; packed b64 P writes
#pragma unroll
    for (int nt = 0; nt < 4; ++nt) {
      f32x4 mv4 = *(const f32x4*)&mkl[nt * 16 + lq * 4];
#pragma unroll
      for (int mi = 0; mi < 2; ++mi) {
        uint2v pk;
        pk.x = pack2bf(__builtin_amdgcn_exp2f(st[nt][mi][0] + mv4[0]),
                       __builtin_amdgcn_exp2f(st[nt][mi][1] + mv4[1]));
        pk.y = pack2bf(__builtin_amdgcn_exp2f(st[nt][mi][2] + mv4[2]),
                       __builtin_amdgcn_exp2f(st[nt][mi][3] + mv4[3]));
        *(uint2v*)&ps[wid][(mi * 16 + lm) * 72 + nt * 16 + lq * 4] = pk;
      }
    }

    // O += P V ; l += P . 1   (ps wave-private: no barrier)
#pragma unroll
    for (int ks2 = 0; ks2 < 2; ++ks2) {
      bf16x8 pf[2], vf[4];
#pragma unroll
      for (int mi = 0; mi < 2; ++mi)
        pf[mi] = *(const bf16x8*)&ps[wid][(mi * 16 + lm) * 72 + ks2 * 32 + lq * 8];
#pragma unroll
      for (int nt = 0; nt < 4; ++nt)
        vf[nt] = *(const bf16x8*)&vs_s[(nt * 16 + lm) * 64 + (((ks2 * 4 + lq) ^ xsw) * 8)];
#pragma unroll
      for (int mi = 0; mi < 2; ++mi) {
#pragma unroll
        for (int nt = 0; nt < 4; ++nt)
          o_acc[mi][nt] = __builtin_amdgcn_mfma_f32_16x16x32_bf16(pf[mi], vf[nt], o_acc[mi][nt], 0, 0, 0);
        l_acc[mi] = __builtin_amdgcn_mfma_f32_16x16x32_bf16(pf[mi], ones, l_acc[mi], 0, 0, 0);
      }
    }
  }

  // epilogue: ao[b, tok, h*64+d] = O/l  (bf16)
#pragma unroll
  for (int mi = 0; mi < 2; ++mi) {
#pragma unroll
    for (int r = 0; r < 4; ++r) {
      float inv = 1.0f / l_acc[mi][r];
      int tok = q0 + mi * 16 + lq * 4 + r;
#pragma unroll
      for (int nt = 0; nt < 4; ++nt)
        ao[(size_t)(bb * 1024 + tok) * 768 + hh * 64 + nt * 16 + lm] = f2bf(o_acc[mi][nt][r] * inv);
    }
  }
}

// ---------------------------------------------------------------------------
// Proj GEMM: M=8192, N=768, K=768.  (unchanged)
// ---------------------------------------------------------------------------
__global__ __launch_bounds__(256)
void proj_gemm(const unsigned short* __restrict__ ab, const unsigned short* __restrict__ wb,
               const float* __restrict__ pb, float* __restrict__ out) {
  __shared__ unsigned short as[128 * 64];   // w rows
  __shared__ unsigned short bs[128 * 64];   // ao rows
  const int tid = threadIdx.x;
  const int lane = tid & 63, wid = tid >> 6;
  const int lm = lane & 15, lq = lane >> 4;
  const int xsw = lm & 7;
  const int wm = (wid & 1) * 64, wn = (wid >> 1) * 64;
  const int L = blockIdx.x;
  const int xcd = L & 7, s = L >> 3;           // s: 0..47
  const int m0 = (xcd * 8 + s / 6) * 128;
  const int n0 = (s % 6) * 128;
  const int srow = lane >> 3;
  const int scolsw = ((lane & 7) ^ srow) * 8;
  const unsigned short* ga = wb + (size_t)(n0 + wid * 32 + srow) * 768 + scolsw;
  const unsigned short* gb = ab + (size_t)(m0 + wid * 32 + srow) * 768 + scolsw;
  f32x4 acc[4][4] = {};
  for (int kt = 0; kt < 768; kt += 64) {
#pragma unroll
    for (int i = 0; i < 4; ++i) {
      gl_lds16(ga + kt + (size_t)i * 8 * 768, &as[(wid * 32 + i * 8) * 64]);
      gl_lds16(gb + kt + (size_t)i * 8 * 768, &bs[(wid * 32 + i * 8) * 64]);
    }
    __syncthreads();
#pragma unroll
    for (int ks = 0; ks < 2; ++ks) {
      bf16x8 af[4], bf[4];
#pragma unroll
      for (int i = 0; i < 4; ++i)
        af[i] = *(const bf16x8*)&as[(wm + i * 16 + lm) * 64 + (((ks * 4 + lq) ^ xsw) * 8)];
#pragma unroll
      for (int i = 0; i < 4; ++i)
        bf[i] = *(const bf16x8*)&bs[(wn + i * 16 + lm) * 64 + (((ks * 4 + lq) ^ xsw) * 8)];
#pragma unroll
      for (int mi = 0; mi < 4; ++mi)
#pragma unroll
        for (int ni = 0; ni < 4; ++ni)
          acc[mi][ni] = __builtin_amdgcn_mfma_f32_16x16x32_bf16(af[mi], bf[ni], acc[mi][ni], 0, 0, 0);
    }
    __syncthreads();
  }
  // acc rows = n-dim, cols = m-dim
#pragma unroll
  for (int mi = 0; mi < 4; ++mi) {
    int gn0 = n0 + wm + mi * 16 + lq * 4;
    f32x4 bias4 = *(const f32x4*)&pb[gn0];
#pragma unroll
    for (int ni = 0; ni < 4; ++ni) {
      int gm = m0 + wn + ni * 16 + lm;
      f32x4 o;
      o[0] = acc[mi][ni][0] + bias4[0];
      o[1] = acc[mi][ni][1] + bias4[1];
      o[2] = acc[mi][ni][2] + bias4[2];
      o[3] = acc[mi][ni][3] + bias4[3];
      *(f32x4*)&out[(size_t)gm * 768 + gn0] = o;
    }
  }
}

// ---------------------------------------------------------------------------
// ws layout (bf16 elts): xb 6291456 | wqkv 1769472 | wproj 589824 |
//   q 6291456 | k 6291456 | v^T 6291456 | ao 6291456   (~67.6 MB)
// ---------------------------------------------------------------------------
extern "C" void kernel_launch(void* const* d_in, const int* in_sizes, int n_in,
                              void* d_out, int out_size, void* d_ws, size_t ws_size,
                              hipStream_t stream) {
  const float* x      = (const float*)d_in[0];
  const int*   mask   = (const int*)d_in[1];
  const float* qkv_w  = (const float*)d_in[2];
  const float* q_bias = (const float*)d_in[3];
  const float* v_bias = (const float*)d_in[4];
  const float* proj_w = (const float*)d_in[5];
  const float* proj_b = (const float*)d_in[6];
  float* out = (float*)d_out;
  unsigned short* p = (unsigned short*)d_ws;
  unsigned short* xb     = p;              p += 6291456;
  unsigned short* wqkvb  = p;              p += 1769472;
  unsigned short* wprojb = p;              p += 589824;
  unsigned short* qo     = p;              p += 6291456;
  unsigned short* ko     = p;              p += 6291456;
  unsigned short* vto    = p;              p += 6291456;
  unsigned short* ao     = p;

  cvt3_kernel<<<8448, 256, 0, stream>>>(x, xb, qkv_w, wqkvb, proj_w, wprojb);
  qkv_gemm<<<256, 512, 0, stream>>>(xb, wqkvb, q_bias, v_bias, qo, ko, vto);
  attn_mfma<<<768, 256, 0, stream>>>(qo, ko, vto, mask, ao);
  proj_gemm<<<384, 256, 0, stream>>>(ao, wprojb, proj_b, out);
}

// Round 3
// 183.088 us; speedup vs baseline: 1.1203x; 1.0069x over previous
//
#include <hip/hip_runtime.h>
#include <cstddef>
#include <cstdint>

// ---------------------------------------------------------------------------
// B=8, N=1024, C=768, H=12, hd=64.  All matmuls mfma_f32_16x16x32_bf16.
// R11: qkv_gemm K-loop merged 4 phases -> 1 compute pass per K-tile with
// minimum fragment reads (26 ds_read_b128/wave/K-tile vs R10's 52 -- R10 was
// LDS-read-BW bound at MfmaUtil 23%).  Barriers 8 -> 2 per K-tile:
//   [reads all frags | stage A1B1(t+1)] -> 40+32 MFMA (2 setprio clusters)
//   -> lgkmcnt(0)+barrier -> stage A0B0(t+2) into read buf -> vmcnt(5|4)
//   +barrier (tile t+1 visible; never drains vmcnt to 0 in loop).
// Geometry unchanged from R10: 288feat x 256tok, 256 blocks, 8 waves,
// 136 KiB LDS dbuf, idempotent dup-stage tail, same epilogues.
// attn_mfma / proj_gemm / cvt3 unchanged.
// ---------------------------------------------------------------------------

typedef __attribute__((ext_vector_type(4))) float f32x4;
typedef __attribute__((ext_vector_type(8))) __bf16 bf16x8;
typedef __attribute__((ext_vector_type(4))) unsigned int uint4v;
typedef __attribute__((ext_vector_type(2))) unsigned int uint2v;

#define QK_PRESCALE 0.18033688011112042f   // 64^-0.5 * log2(e); softmax uses exp2

// round-half-up bf16: max error 0.5 ulp
__device__ __forceinline__ unsigned short f2bf(float f) {
  return (unsigned short)((__float_as_uint(f) + 0x8000u) >> 16);
}
// pack two floats -> bf16x2 in one v_perm_b32
__device__ __forceinline__ unsigned int pack2bf(float flo, float fhi) {
  unsigned ulo = __float_as_uint(flo) + 0x8000u;
  unsigned uhi = __float_as_uint(fhi) + 0x8000u;
  return __builtin_amdgcn_perm(uhi, ulo, 0x07060302);
}

// one wave instruction: 64 lanes x 16 B -> LDS[base + lane*16]
__device__ __forceinline__ void gl_lds16(const unsigned short* g, unsigned short* l) {
  __builtin_amdgcn_global_load_lds(
      (const __attribute__((address_space(1))) unsigned int*)g,
      (__attribute__((address_space(3))) unsigned int*)l, 16, 0, 0);
}

// ---------------------------------------------------------------------------
// fp32 -> bf16 conversion for x / qkv_w / proj_w in ONE launch.
// ---------------------------------------------------------------------------
__global__ __launch_bounds__(256)
void cvt3_kernel(const float* __restrict__ s0, unsigned short* __restrict__ d0,
                 const float* __restrict__ s1, unsigned short* __restrict__ d1,
                 const float* __restrict__ s2, unsigned short* __restrict__ d2) {
  int bid = blockIdx.x;
  const float* s; unsigned short* d; int i; int n4;
  if (bid < 6144)      { s = s0; d = d0; i = bid * 256 + threadIdx.x;            n4 = 1572864; }
  else if (bid < 7872) { s = s1; d = d1; i = (bid - 6144) * 256 + threadIdx.x;   n4 = 442368; }
  else                 { s = s2; d = d2; i = (bid - 7872) * 256 + threadIdx.x;   n4 = 147456; }
  if (i < n4) {
    float4 v = ((const float4*)s)[i];
    uint2v o;
    o.x = pack2bf(v.x, v.y);
    o.y = pack2bf(v.z, v.w);
    ((uint2v*)d)[i] = o;
  }
}

// staging row tables (wave-uniform).  A tile = 288 rows; 8-row chunks.
// Ga0 = rows [0,80) u [144,224)  (20 ops); Ga1 = rows [80,144) u [224,288) (16)
__device__ __forceinline__ int a0row(int o) { return (o < 10) ? o * 8 : 144 + (o - 10) * 8; }
__device__ __forceinline__ int a1row(int o) { return (o < 8) ? 80 + o * 8 : 224 + (o - 8) * 8; }

// ---------------------------------------------------------------------------
// QKV GEMM: A = wqkv (2304 feature rows), B = x (8192 token rows), K = 768.
// Tile: 288 feat x 256 tok, 8 waves (wr=feat-half of 144, wc=tok-quarter of 64).
// LDS shorts: A dbuf [0, 36864) (2 x 288 x 64) | B dbuf [36864, 69632).
// Per K-tile t (buf b = t&1):
//   A: 26 ds_read_b128 (bff[4][2], af[5][2], later af2[4][2]) from buf b
//   B: STAGE A1,B1(t+1) -> buf b^1      (4 ops/wave)
//   C: 40 MFMA rows0-4 | D: 32 MFMA rows5-8   (setprio clusters)
//   E: lgkmcnt(0) + s_barrier           (all waves done reading buf b)
//   F: STAGE A0,B0(t+2) -> buf b        (5 ops waves0-3, 4 ops waves4-7)
//   G: vmcnt(5|4) + s_barrier           (tile t+1 fully visible)
// Tail t>=10 stages clamp to tile 11 -> idempotent duplicate loads.
// ---------------------------------------------------------------------------
__global__ __launch_bounds__(512, 2)
void qkv_gemm(const unsigned short* __restrict__ xb, const unsigned short* __restrict__ wb,
              const float* __restrict__ qb, const float* __restrict__ vb,
              unsigned short* __restrict__ qo, unsigned short* __restrict__ ko,
              unsigned short* __restrict__ vto) {
  __shared__ __align__(16) unsigned short lds[69632];  // 136 KiB
  const int tid = threadIdx.x;
  const int lane = tid & 63, wid = tid >> 6;
  const int widu = __builtin_amdgcn_readfirstlane(wid);
  const int lm = lane & 15, lq = lane >> 4;
  const int xsw = lm & 7;
  const int wr = widu >> 2, wc = widu & 3;      // feat-half, tok-quarter
  const int L = blockIdx.x;
  const int xcd = L & 7, s = L >> 3;            // s: 0..31
  const int tt = xcd * 4 + (s >> 3);            // token tile 0..31
  const int ft = s & 7;                         // feature tile 0..7
  const int m0 = tt * 256;                      // token base
  const int n0 = ft * 288;                      // feature base
  const int srow = lane >> 3;                   // 0..7
  const int scolsw = ((lane & 7) ^ srow) * 8;   // pre-swizzled source chunk
  const unsigned short* paS = wb + (size_t)(n0 + srow) * 768 + scolsw;
  const unsigned short* pbS = xb + (size_t)(m0 + srow) * 768 + scolsw;

  // per-wave stage rows (SGPR via widu)
  const int a0n3 = (widu < 4);
  const int a0o = a0n3 ? widu * 3 : 12 + (widu - 4) * 2;
  const int a0r0 = a0row(a0o), a0r1 = a0row(a0o + 1);
  const int a0r2 = a0n3 ? a0row(a0o + 2) : 0;
  const int a1r0 = a1row(2 * widu), a1r1 = a1row(2 * widu + 1);
  const int b0q0 = (2 * widu) >> 2, b0q1 = (2 * widu + 1) >> 2;
  const int b0r0 = b0q0 * 64 + ((2 * widu) & 3) * 8;
  const int b0r1 = b0q1 * 64 + ((2 * widu + 1) & 3) * 8;
  const int b1r0 = b0r0 + 32, b1r1 = b0r1 + 32;

  f32x4 acc[9][4] = {};

#define STAGE_A0(tgt) { const size_t _c = (size_t)(tgt) * 64; const int _b = ((tgt) & 1) * 18432; \
    gl_lds16(paS + (size_t)a0r0 * 768 + _c, &lds[_b + a0r0 * 64]); \
    gl_lds16(paS + (size_t)a0r1 * 768 + _c, &lds[_b + a0r1 * 64]); \
    if (a0n3) gl_lds16(paS + (size_t)a0r2 * 768 + _c, &lds[_b + a0r2 * 64]); }

#define STAGE_A1(tgt) { const size_t _c = (size_t)(tgt) * 64; const int _b = ((tgt) & 1) * 18432; \
    gl_lds16(paS + (size_t)a1r0 * 768 + _c, &lds[_b + a1r0 * 64]); \
    gl_lds16(paS + (size_t)a1r1 * 768 + _c, &lds[_b + a1r1 * 64]); }

#define STAGE_B0(tgt) { const size_t _c = (size_t)(tgt) * 64; const int _b = 36864 + ((tgt) & 1) * 16384; \
    gl_lds16(pbS + (size_t)b0r0 * 768 + _c, &lds[_b + b0r0 * 64]); \
    gl_lds16(pbS + (size_t)b0r1 * 768 + _c, &lds[_b + b0r1 * 64]); }

#define STAGE_B1(tgt) { const size_t _c = (size_t)(tgt) * 64; const int _b = 36864 + ((tgt) & 1) * 16384; \
    gl_lds16(pbS + (size_t)b1r0 * 768 + _c, &lds[_b + b1r0 * 64]); \
    gl_lds16(pbS + (size_t)b1r1 * 768 + _c, &lds[_b + b1r1 * 64]); }

#define WAIT_G() { if (a0n3) asm volatile("s_waitcnt vmcnt(5)" ::: "memory"); \
                   else      asm volatile("s_waitcnt vmcnt(4)" ::: "memory"); \
                   asm volatile("s_barrier" ::: "memory"); }
#define BAR_E()   asm volatile("s_waitcnt lgkmcnt(0)\ns_barrier" ::: "memory")

  // prologue: tile 0 (all groups) then tile 1 (A0,B0).  FIFO order matters.
  STAGE_A0(0); STAGE_B0(0); STAGE_A1(0); STAGE_B1(0);
  STAGE_A0(1); STAGE_B0(1);
  WAIT_G();   // tile 0 visible

  for (int t = 0; t < 12; ++t) {
    const int b = t & 1;
    const int tn1 = (t + 1 < 12) ? t + 1 : 11;
    const int tn2 = (t + 2 < 12) ? t + 2 : 11;
    const unsigned short* Ab = &lds[b * 18432];
    const unsigned short* Bb = &lds[36864 + b * 16384];

    // A: fragment loads (compiler schedules lgkm fine-grained)
    bf16x8 bff[4][2], af[5][2];
#pragma unroll
    for (int n2 = 0; n2 < 4; ++n2)
#pragma unroll
      for (int kx = 0; kx < 2; ++kx)
        bff[n2][kx] = *(const bf16x8*)&Bb[(wc * 64 + n2 * 16 + lm) * 64 + (((kx * 4 + lq) ^ xsw) * 8)];
#pragma unroll
    for (int m2 = 0; m2 < 5; ++m2)
#pragma unroll
      for (int kx = 0; kx < 2; ++kx)
        af[m2][kx] = *(const bf16x8*)&Ab[(wr * 144 + m2 * 16 + lm) * 64 + (((kx * 4 + lq) ^ xsw) * 8)];

    // B: stage A1,B1 of next tile into the other buffer
    STAGE_A1(tn1); STAGE_B1(tn1);

    // C: cluster 1 — rows 0-4 x all cols (40 MFMA)
    __builtin_amdgcn_s_setprio(1);
#pragma unroll
    for (int kx = 0; kx < 2; ++kx)
#pragma unroll
      for (int m2 = 0; m2 < 5; ++m2)
#pragma unroll
        for (int n2 = 0; n2 < 4; ++n2)
          acc[m2][n2] = __builtin_amdgcn_mfma_f32_16x16x32_bf16(af[m2][kx], bff[n2][kx], acc[m2][n2], 0, 0, 0);
    __builtin_amdgcn_s_setprio(0);

    // D: cluster 2 — rows 5-8 (af2 replaces af; bff still live)
    bf16x8 af2[4][2];
#pragma unroll
    for (int m2 = 0; m2 < 4; ++m2)
#pragma unroll
      for (int kx = 0; kx < 2; ++kx)
        af2[m2][kx] = *(const bf16x8*)&Ab[(wr * 144 + (5 + m2) * 16 + lm) * 64 + (((kx * 4 + lq) ^ xsw) * 8)];
    __builtin_amdgcn_s_setprio(1);
#pragma unroll
    for (int kx = 0; kx < 2; ++kx)
#pragma unroll
      for (int m2 = 0; m2 < 4; ++m2)
#pragma unroll
        for (int n2 = 0; n2 < 4; ++n2)
          acc[5 + m2][n2] = __builtin_amdgcn_mfma_f32_16x16x32_bf16(af2[m2][kx], bff[n2][kx], acc[5 + m2][n2], 0, 0, 0);
    __builtin_amdgcn_s_setprio(0);

    // E: all waves done reading buf b -> safe to stage into it
    BAR_E();
    // F: stage A0,B0 of tile t+2 into buf b
    STAGE_A0(tn2); STAGE_B0(tn2);
    // G: tile t+1 fully staged (keep newest group in flight)
    WAIT_G();
  }
  asm volatile("s_waitcnt vmcnt(0)" ::: "memory");  // drain tail dup-stages

#undef STAGE_A0
#undef STAGE_A1
#undef STAGE_B0
#undef STAGE_B1

  // ---------------- epilogue ----------------
  const int bq = tt >> 2;               // batch
  const int tokb = (tt & 3) * 256;      // token offset within batch
  // q/k rowblocks: direct packed 8B stores (4 consecutive d per lane)
#pragma unroll
  for (int mi = 0; mi < 9; ++mi) {
    const int fblk = n0 + wr * 144 + mi * 16;   // 16-aligned; q/k/v boundary safe
    if (fblk < 1536) {
      const bool isq = fblk < 768;
      unsigned short* dst0 = isq ? qo : ko;
      const int fd = fblk - (isq ? 0 : 768);
      const int hh = fd >> 6;
      const int dih = (fd & 63) + lq * 4;
      f32x4 bias4 = {0.f, 0.f, 0.f, 0.f};
      if (isq) bias4 = *(const f32x4*)&qb[fblk + lq * 4];
#pragma unroll
      for (int ni = 0; ni < 4; ++ni) {
        const int tok = tokb + wc * 64 + ni * 16 + lm;
        uint2v pk;
        if (isq) {
          pk.x = pack2bf((acc[mi][ni][0] + bias4[0]) * QK_PRESCALE,
                         (acc[mi][ni][1] + bias4[1]) * QK_PRESCALE);
          pk.y = pack2bf((acc[mi][ni][2] + bias4[2]) * QK_PRESCALE,
                         (acc[mi][ni][3] + bias4[3]) * QK_PRESCALE);
        } else {
          pk.x = pack2bf(acc[mi][ni][0], acc[mi][ni][1]);
          pk.y = pack2bf(acc[mi][ni][2], acc[mi][ni][3]);
        }
        *(uint2v*)&dst0[(((size_t)(bq * 12 + hh)) * 1024 + tok) * 64 + dih] = pk;
      }
    }
  }
  // v rowblocks: transpose via LDS scratch (144 x stride 264), 2 passes
  if (n0 + 288 > 1536) {
#pragma unroll
    for (int p = 0; p < 2; ++p) {
      __syncthreads();
      if (wr == p) {
#pragma unroll
        for (int mi = 0; mi < 9; ++mi) {
          const int fblk = n0 + p * 144 + mi * 16;
          if (fblk >= 1536) {
            f32x4 bias4 = *(const f32x4*)&vb[fblk - 1536 + lq * 4];
#pragma unroll
            for (int ni = 0; ni < 4; ++ni) {
              const int tokl = wc * 64 + ni * 16 + lm;
#pragma unroll
              for (int r = 0; r < 4; ++r)
                lds[(mi * 16 + lq * 4 + r) * 264 + tokl] = f2bf(acc[mi][ni][r] + bias4[r]);
            }
          }
        }
      }
      __syncthreads();
      const int fv = 1536 - (n0 + p * 144);
      const int rv0 = fv > 0 ? fv : 0;
      for (int r = rv0 + (tid >> 2); r < 144; r += 128) {
        const int tq = tid & 3;
        const int dgv = n0 + p * 144 + r - 1536;      // 0..767
        const int hh = dgv >> 6, d = dgv & 63;
        unsigned short* dstv = vto + (((size_t)(bq * 12 + hh)) * 64 + d) * 1024 + tokb + tq * 64;
        const unsigned short* srcr = &lds[r * 264 + tq * 64];
#pragma unroll
        for (int j = 0; j < 8; ++j)
          *(uint4v*)&dstv[j * 8] = *(const uint4v*)&srcr[j * 8];
      }
    }
  }
}

// ---------------------------------------------------------------------------
// Flash attention. 768 blocks = 8 XCD x (12 bh x 8 q-tiles).  (unchanged)
// ---------------------------------------------------------------------------
__global__ __launch_bounds__(256)
void attn_mfma(const unsigned short* __restrict__ q, const unsigned short* __restrict__ k,
               const unsigned short* __restrict__ vt, const int* __restrict__ mask,
               unsigned short* __restrict__ ao) {
  __shared__ unsigned short ks_s[64 * 64];     // [key][hd], swizzled chunks
  __shared__ unsigned short vs_s[64 * 64];     // [hd][key], swizzled chunks
  __shared__ unsigned short ps[4][32 * 72];    // per-wave P [q][key], stride 72
  __shared__ float mkl[64];
  const int tid = threadIdx.x;
  const int lane = tid & 63, wid = tid >> 6;
  const int lm = lane & 15, lq = lane >> 4;
  const int xsw = lm & 7;
  const int L = blockIdx.x;
  const int xcd = L & 7, s = L >> 3;           // s: 0..95
  const int bh = xcd * 12 + s / 8;
  const int qt = s % 8;
  const int bb = bh / 12, hh = bh % 12;
  const unsigned short* qp = q + (size_t)bh * 65536;
  const unsigned short* kp = k + (size_t)bh * 65536;
  const unsigned short* vp = vt + (size_t)bh * 65536;
  const int* mp = mask + bb * 1024;
  const int q0 = qt * 128 + wid * 32;
  const int srow = lane >> 3;
  const int scolsw = ((lane & 7) ^ srow) * 8;
  const unsigned short* gk = kp + (size_t)(wid * 16 + srow) * 64 + scolsw;
  const unsigned short* gv = vp + (size_t)(wid * 16 + srow) * 1024 + scolsw;

  bf16x8 qf[2][2];
#pragma unroll
  for (int mi = 0; mi < 2; ++mi)
#pragma unroll
    for (int ks2 = 0; ks2 < 2; ++ks2)
      qf[mi][ks2] = *(const bf16x8*)&qp[(size_t)(q0 + mi * 16 + lm) * 64 + ks2 * 32 + lq * 8];
  bf16x8 ones;
#pragma unroll
  for (int i = 0; i < 8; ++i) ones[i] = (__bf16)1.0f;

  f32x4 o_acc[2][4] = {};
  f32x4 l_acc[2] = {};

  for (int kt = 0; kt < 16; ++kt) {
    __syncthreads();                           // drain prior tile reads
#pragma unroll
    for (int i = 0; i < 2; ++i) {
      gl_lds16(gk + (size_t)kt * 4096 + (size_t)i * 8 * 64, &ks_s[(wid * 16 + i * 8) * 64]);
      gl_lds16(gv + (size_t)kt * 64 + (size_t)i * 8 * 1024, &vs_s[(wid * 16 + i * 8) * 64]);
    }
    if (tid < 64) mkl[tid] = mp[kt * 64 + tid] ? -1e30f : 0.0f;
    __syncthreads();

    // S^T = K Q^T : tile [key-tile nt][q-tile mi]; col=q=lm, row=key=lq*4+r
    f32x4 st[4][2] = {};
#pragma unroll
    for (int ks2 = 0; ks2 < 2; ++ks2) {
      bf16x8 kf[4];
#pragma unroll
      for (int nt = 0; nt < 4; ++nt)
        kf[nt] = *(const bf16x8*)&ks_s[(nt * 16 + lm) * 64 + (((ks2 * 4 + lq) ^ xsw) * 8)];
#pragma unroll
      for (int nt = 0; nt < 4; ++nt)
#pragma unroll
        for (int mi = 0; mi < 2; ++mi)
          st[nt][mi] = __builtin_amdgcn_mfma_f32_16x16x32_bf16(kf[nt], qf[mi][ks2], st[nt][mi], 0, 0, 0);
    }

    // p = exp2(st + mask[key]) via raw v_exp_f32; packed b64 P writes
#pragma unroll
    for (int nt = 0; nt < 4; ++nt) {
      f32x4 mv4 = *(const f32x4*)&mkl[nt * 16 + lq * 4];
#pragma unroll
      for (int mi = 0; mi < 2; ++mi) {
        uint2v pk;
        pk.x = pack2bf(__builtin_amdgcn_exp2f(st[nt][mi][0] + mv4[0]),
                       __builtin_amdgcn_exp2f(st[nt][mi][1] + mv4[1]));
        pk.y = pack2bf(__builtin_amdgcn_exp2f(st[nt][mi][2] + mv4[2]),
                       __builtin_amdgcn_exp2f(st[nt][mi][3] + mv4[3]));
        *(uint2v*)&ps[wid][(mi * 16 + lm) * 72 + nt * 16 + lq * 4] = pk;
      }
    }

    // O += P V ; l += P . 1   (ps wave-private: no barrier)
#pragma unroll
    for (int ks2 = 0; ks2 < 2; ++ks2) {
      bf16x8 pf[2], vf[4];
#pragma unroll
      for (int mi = 0; mi < 2; ++mi)
        pf[mi] = *(const bf16x8*)&ps[wid][(mi * 16 + lm) * 72 + ks2 * 32 + lq * 8];
#pragma unroll
      for (int nt = 0; nt < 4; ++nt)
        vf[nt] = *(const bf16x8*)&vs_s[(nt * 16 + lm) * 64 + (((ks2 * 4 + lq) ^ xsw) * 8)];
#pragma unroll
      for (int mi = 0; mi < 2; ++mi) {
#pragma unroll
        for (int nt = 0; nt < 4; ++nt)
          o_acc[mi][nt] = __builtin_amdgcn_mfma_f32_16x16x32_bf16(pf[mi], vf[nt], o_acc[mi][nt], 0, 0, 0);
        l_acc[mi] = __builtin_amdgcn_mfma_f32_16x16x32_bf16(pf[mi], ones, l_acc[mi], 0, 0, 0);
      }
    }
  }

  // epilogue: ao[b, tok, h*64+d] = O/l  (bf16)
#pragma unroll
  for (int mi = 0; mi < 2; ++mi) {
#pragma unroll
    for (int r = 0; r < 4; ++r) {
      float inv = 1.0f / l_acc[mi][r];
      int tok = q0 + mi * 16 + lq * 4 + r;
#pragma unroll
      for (int nt = 0; nt < 4; ++nt)
        ao[(size_t)(bb * 1024 + tok) * 768 + hh * 64 + nt * 16 + lm] = f2bf(o_acc[mi][nt][r] * inv);
    }
  }
}

// ---------------------------------------------------------------------------
// Proj GEMM: M=8192, N=768, K=768.  (unchanged)
// ---------------------------------------------------------------------------
__global__ __launch_bounds__(256)
void proj_gemm(const unsigned short* __restrict__ ab, const unsigned short* __restrict__ wb,
               const float* __restrict__ pb, float* __restrict__ out) {
  __shared__ unsigned short as[128 * 64];   // w rows
  __shared__ unsigned short bs[128 * 64];   // ao rows
  const int tid = threadIdx.x;
  const int lane = tid & 63, wid = tid >> 6;
  const int lm = lane & 15, lq = lane >> 4;
  const int xsw = lm & 7;
  const int wm = (wid & 1) * 64, wn = (wid >> 1) * 64;
  const int L = blockIdx.x;
  const int xcd = L & 7, s = L >> 3;           // s: 0..47
  const int m0 = (xcd * 8 + s / 6) * 128;
  const int n0 = (s % 6) * 128;
  const int srow = lane >> 3;
  const int scolsw = ((lane & 7) ^ srow) * 8;
  const unsigned short* ga = wb + (size_t)(n0 + wid * 32 + srow) * 768 + scolsw;
  const unsigned short* gb = ab + (size_t)(m0 + wid * 32 + srow) * 768 + scolsw;
  f32x4 acc[4][4] = {};
  for (int kt = 0; kt < 768; kt += 64) {
#pragma unroll
    for (int i = 0; i < 4; ++i) {
      gl_lds16(ga + kt + (size_t)i * 8 * 768, &as[(wid * 32 + i * 8) * 64]);
      gl_lds16(gb + kt + (size_t)i * 8 * 768, &bs[(wid * 32 + i * 8) * 64]);
    }
    __syncthreads();
#pragma unroll
    for (int ks = 0; ks < 2; ++ks) {
      bf16x8 af[4], bf[4];
#pragma unroll
      for (int i = 0; i < 4; ++i)
        af[i] = *(const bf16x8*)&as[(wm + i * 16 + lm) * 64 + (((ks * 4 + lq) ^ xsw) * 8)];
#pragma unroll
      for (int i = 0; i < 4; ++i)
        bf[i] = *(const bf16x8*)&bs[(wn + i * 16 + lm) * 64 + (((ks * 4 + lq) ^ xsw) * 8)];
#pragma unroll
      for (int mi = 0; mi < 4; ++mi)
#pragma unroll
        for (int ni = 0; ni < 4; ++ni)
          acc[mi][ni] = __builtin_amdgcn_mfma_f32_16x16x32_bf16(af[mi], bf[ni], acc[mi][ni], 0, 0, 0);
    }
    __syncthreads();
  }
  // acc rows = n-dim, cols = m-dim
#pragma unroll
  for (int mi = 0; mi < 4; ++mi) {
    int gn0 = n0 + wm + mi * 16 + lq * 4;
    f32x4 bias4 = *(const f32x4*)&pb[gn0];
#pragma unroll
    for (int ni = 0; ni < 4; ++ni) {
      int gm = m0 + wn + ni * 16 + lm;
      f32x4 o;
      o[0] = acc[mi][ni][0] + bias4[0];
      o[1] = acc[mi][ni][1] + bias4[1];
      o[2] = acc[mi][ni][2] + bias4[2];
      o[3] = acc[mi][ni][3] + bias4[3];
      *(f32x4*)&out[(size_t)gm * 768 + gn0] = o;
    }
  }
}

// ---------------------------------------------------------------------------
// ws layout (bf16 elts): xb 6291456 | wqkv 1769472 | wproj 589824 |
//   q 6291456 | k 6291456 | v^T 6291456 | ao 6291456   (~67.6 MB)
// ---------------------------------------------------------------------------
extern "C" void kernel_launch(void* const* d_in, const int* in_sizes, int n_in,
                              void* d_out, int out_size, void* d_ws, size_t ws_size,
                              hipStream_t stream) {
  const float* x      = (const float*)d_in[0];
  const int*   mask   = (const int*)d_in[1];
  const float* qkv_w  = (const float*)d_in[2];
  const float* q_bias = (const float*)d_in[3];
  const float* v_bias = (const float*)d_in[4];
  const float* proj_w = (const float*)d_in[5];
  const float* proj_b = (const float*)d_in[6];
  float* out = (float*)d_out;
  unsigned short* p = (unsigned short*)d_ws;
  unsigned short* xb     = p;              p += 6291456;
  unsigned short* wqkvb  = p;              p += 1769472;
  unsigned short* wprojb = p;              p += 589824;
  unsigned short* qo     = p;              p += 6291456;
  unsigned short* ko     = p;              p += 6291456;
  unsigned short* vto    = p;              p += 6291456;
  unsigned short* ao     = p;

  cvt3_kernel<<<8448, 256, 0, stream>>>(x, xb, qkv_w, wqkvb, proj_w, wprojb);
  qkv_gemm<<<256, 512, 0, stream>>>(xb, wqkvb, q_bias, v_bias, qo, ko, vto);
  attn_mfma<<<768, 256, 0, stream>>>(qo, ko, vto, mask, ao);
  proj_gemm<<<384, 256, 0, stream>>>(ao, wprojb, proj_b, out);
}

// Round 4
// 182.131 us; speedup vs baseline: 1.1262x; 1.0053x over previous
//
#include <hip/hip_runtime.h>
#include <cstddef>
#include <cstdint>

// ---------------------------------------------------------------------------
// B=8, N=1024, C=768, H=12, hd=64.  All matmuls mfma_f32_16x16x32_bf16.
// R12: attn_mfma rebuilt: (1) K/V double-buffered with async 1-deep prefetch
// (issue tile t+1 gl_lds right after tile-t barrier, wait vmcnt(0)+barrier at
// tile end -> zero exposed load latency, 1 barrier/tile vs 2);  (2) ps halved
// (PV per 32-key half) so LDS = 46KB keeps 3 blocks/CU;  (3) ps re-strided to
// 40 shorts + 8B-granular XOR (^((lm&8)>>1)) col swizzle, reads b128->2xb64:
// conflict-free both sides (R11 ps was 2.36M bank-conflict cycles);  (4) mask
// hoisted to mkl[1024] once in prologue.
// qkv_gemm / proj_gemm / cvt3 unchanged from R11.
// ---------------------------------------------------------------------------

typedef __attribute__((ext_vector_type(4))) float f32x4;
typedef __attribute__((ext_vector_type(8))) __bf16 bf16x8;
typedef __attribute__((ext_vector_type(4))) unsigned int uint4v;
typedef __attribute__((ext_vector_type(2))) unsigned int uint2v;

#define QK_PRESCALE 0.18033688011112042f   // 64^-0.5 * log2(e); softmax uses exp2

// round-half-up bf16: max error 0.5 ulp
__device__ __forceinline__ unsigned short f2bf(float f) {
  return (unsigned short)((__float_as_uint(f) + 0x8000u) >> 16);
}
// pack two floats -> bf16x2 in one v_perm_b32
__device__ __forceinline__ unsigned int pack2bf(float flo, float fhi) {
  unsigned ulo = __float_as_uint(flo) + 0x8000u;
  unsigned uhi = __float_as_uint(fhi) + 0x8000u;
  return __builtin_amdgcn_perm(uhi, ulo, 0x07060302);
}

// one wave instruction: 64 lanes x 16 B -> LDS[base + lane*16]
__device__ __forceinline__ void gl_lds16(const unsigned short* g, unsigned short* l) {
  __builtin_amdgcn_global_load_lds(
      (const __attribute__((address_space(1))) unsigned int*)g,
      (__attribute__((address_space(3))) unsigned int*)l, 16, 0, 0);
}

// ---------------------------------------------------------------------------
// fp32 -> bf16 conversion for x / qkv_w / proj_w in ONE launch.
// ---------------------------------------------------------------------------
__global__ __launch_bounds__(256)
void cvt3_kernel(const float* __restrict__ s0, unsigned short* __restrict__ d0,
                 const float* __restrict__ s1, unsigned short* __restrict__ d1,
                 const float* __restrict__ s2, unsigned short* __restrict__ d2) {
  int bid = blockIdx.x;
  const float* s; unsigned short* d; int i; int n4;
  if (bid < 6144)      { s = s0; d = d0; i = bid * 256 + threadIdx.x;            n4 = 1572864; }
  else if (bid < 7872) { s = s1; d = d1; i = (bid - 6144) * 256 + threadIdx.x;   n4 = 442368; }
  else                 { s = s2; d = d2; i = (bid - 7872) * 256 + threadIdx.x;   n4 = 147456; }
  if (i < n4) {
    float4 v = ((const float4*)s)[i];
    uint2v o;
    o.x = pack2bf(v.x, v.y);
    o.y = pack2bf(v.z, v.w);
    ((uint2v*)d)[i] = o;
  }
}

// staging row tables (wave-uniform).  A tile = 288 rows; 8-row chunks.
// Ga0 = rows [0,80) u [144,224)  (20 ops); Ga1 = rows [80,144) u [224,288) (16)
__device__ __forceinline__ int a0row(int o) { return (o < 10) ? o * 8 : 144 + (o - 10) * 8; }
__device__ __forceinline__ int a1row(int o) { return (o < 8) ? 80 + o * 8 : 224 + (o - 8) * 8; }

// ---------------------------------------------------------------------------
// QKV GEMM: A = wqkv (2304 feature rows), B = x (8192 token rows), K = 768.
// (R11 structure: 288x256 tile, 256 blocks, single-pass K-tile with 26
// ds_read_b128/wave, 2 barriers/K-tile, counted vmcnt.)
// ---------------------------------------------------------------------------
__global__ __launch_bounds__(512, 2)
void qkv_gemm(const unsigned short* __restrict__ xb, const unsigned short* __restrict__ wb,
              const float* __restrict__ qb, const float* __restrict__ vb,
              unsigned short* __restrict__ qo, unsigned short* __restrict__ ko,
              unsigned short* __restrict__ vto) {
  __shared__ __align__(16) unsigned short lds[69632];  // 136 KiB
  const int tid = threadIdx.x;
  const int lane = tid & 63, wid = tid >> 6;
  const int widu = __builtin_amdgcn_readfirstlane(wid);
  const int lm = lane & 15, lq = lane >> 4;
  const int xsw = lm & 7;
  const int wr = widu >> 2, wc = widu & 3;      // feat-half, tok-quarter
  const int L = blockIdx.x;
  const int xcd = L & 7, s = L >> 3;            // s: 0..31
  const int tt = xcd * 4 + (s >> 3);            // token tile 0..31
  const int ft = s & 7;                         // feature tile 0..7
  const int m0 = tt * 256;                      // token base
  const int n0 = ft * 288;                      // feature base
  const int srow = lane >> 3;                   // 0..7
  const int scolsw = ((lane & 7) ^ srow) * 8;   // pre-swizzled source chunk
  const unsigned short* paS = wb + (size_t)(n0 + srow) * 768 + scolsw;
  const unsigned short* pbS = xb + (size_t)(m0 + srow) * 768 + scolsw;

  // per-wave stage rows (SGPR via widu)
  const int a0n3 = (widu < 4);
  const int a0o = a0n3 ? widu * 3 : 12 + (widu - 4) * 2;
  const int a0r0 = a0row(a0o), a0r1 = a0row(a0o + 1);
  const int a0r2 = a0n3 ? a0row(a0o + 2) : 0;
  const int a1r0 = a1row(2 * widu), a1r1 = a1row(2 * widu + 1);
  const int b0q0 = (2 * widu) >> 2, b0q1 = (2 * widu + 1) >> 2;
  const int b0r0 = b0q0 * 64 + ((2 * widu) & 3) * 8;
  const int b0r1 = b0q1 * 64 + ((2 * widu + 1) & 3) * 8;
  const int b1r0 = b0r0 + 32, b1r1 = b0r1 + 32;

  f32x4 acc[9][4] = {};

#define STAGE_A0(tgt) { const size_t _c = (size_t)(tgt) * 64; const int _b = ((tgt) & 1) * 18432; \
    gl_lds16(paS + (size_t)a0r0 * 768 + _c, &lds[_b + a0r0 * 64]); \
    gl_lds16(paS + (size_t)a0r1 * 768 + _c, &lds[_b + a0r1 * 64]); \
    if (a0n3) gl_lds16(paS + (size_t)a0r2 * 768 + _c, &lds[_b + a0r2 * 64]); }

#define STAGE_A1(tgt) { const size_t _c = (size_t)(tgt) * 64; const int _b = ((tgt) & 1) * 18432; \
    gl_lds16(paS + (size_t)a1r0 * 768 + _c, &lds[_b + a1r0 * 64]); \
    gl_lds16(paS + (size_t)a1r1 * 768 + _c, &lds[_b + a1r1 * 64]); }

#define STAGE_B0(tgt) { const size_t _c = (size_t)(tgt) * 64; const int _b = 36864 + ((tgt) & 1) * 16384; \
    gl_lds16(pbS + (size_t)b0r0 * 768 + _c, &lds[_b + b0r0 * 64]); \
    gl_lds16(pbS + (size_t)b0r1 * 768 + _c, &lds[_b + b0r1 * 64]); }

#define STAGE_B1(tgt) { const size_t _c = (size_t)(tgt) * 64; const int _b = 36864 + ((tgt) & 1) * 16384; \
    gl_lds16(pbS + (size_t)b1r0 * 768 + _c, &lds[_b + b1r0 * 64]); \
    gl_lds16(pbS + (size_t)b1r1 * 768 + _c, &lds[_b + b1r1 * 64]); }

#define WAIT_G() { if (a0n3) asm volatile("s_waitcnt vmcnt(5)" ::: "memory"); \
                   else      asm volatile("s_waitcnt vmcnt(4)" ::: "memory"); \
                   asm volatile("s_barrier" ::: "memory"); }
#define BAR_E()   asm volatile("s_waitcnt lgkmcnt(0)\ns_barrier" ::: "memory")

  // prologue: tile 0 (all groups) then tile 1 (A0,B0).  FIFO order matters.
  STAGE_A0(0); STAGE_B0(0); STAGE_A1(0); STAGE_B1(0);
  STAGE_A0(1); STAGE_B0(1);
  WAIT_G();   // tile 0 visible

  for (int t = 0; t < 12; ++t) {
    const int b = t & 1;
    const int tn1 = (t + 1 < 12) ? t + 1 : 11;
    const int tn2 = (t + 2 < 12) ? t + 2 : 11;
    const unsigned short* Ab = &lds[b * 18432];
    const unsigned short* Bb = &lds[36864 + b * 16384];

    // A: fragment loads (compiler schedules lgkm fine-grained)
    bf16x8 bff[4][2], af[5][2];
#pragma unroll
    for (int n2 = 0; n2 < 4; ++n2)
#pragma unroll
      for (int kx = 0; kx < 2; ++kx)
        bff[n2][kx] = *(const bf16x8*)&Bb[(wc * 64 + n2 * 16 + lm) * 64 + (((kx * 4 + lq) ^ xsw) * 8)];
#pragma unroll
    for (int m2 = 0; m2 < 5; ++m2)
#pragma unroll
      for (int kx = 0; kx < 2; ++kx)
        af[m2][kx] = *(const bf16x8*)&Ab[(wr * 144 + m2 * 16 + lm) * 64 + (((kx * 4 + lq) ^ xsw) * 8)];

    // B: stage A1,B1 of next tile into the other buffer
    STAGE_A1(tn1); STAGE_B1(tn1);

    // C: cluster 1 — rows 0-4 x all cols (40 MFMA)
    __builtin_amdgcn_s_setprio(1);
#pragma unroll
    for (int kx = 0; kx < 2; ++kx)
#pragma unroll
      for (int m2 = 0; m2 < 5; ++m2)
#pragma unroll
        for (int n2 = 0; n2 < 4; ++n2)
          acc[m2][n2] = __builtin_amdgcn_mfma_f32_16x16x32_bf16(af[m2][kx], bff[n2][kx], acc[m2][n2], 0, 0, 0);
    __builtin_amdgcn_s_setprio(0);

    // D: cluster 2 — rows 5-8 (af2 replaces af; bff still live)
    bf16x8 af2[4][2];
#pragma unroll
    for (int m2 = 0; m2 < 4; ++m2)
#pragma unroll
      for (int kx = 0; kx < 2; ++kx)
        af2[m2][kx] = *(const bf16x8*)&Ab[(wr * 144 + (5 + m2) * 16 + lm) * 64 + (((kx * 4 + lq) ^ xsw) * 8)];
    __builtin_amdgcn_s_setprio(1);
#pragma unroll
    for (int kx = 0; kx < 2; ++kx)
#pragma unroll
      for (int m2 = 0; m2 < 4; ++m2)
#pragma unroll
        for (int n2 = 0; n2 < 4; ++n2)
          acc[5 + m2][n2] = __builtin_amdgcn_mfma_f32_16x16x32_bf16(af2[m2][kx], bff[n2][kx], acc[5 + m2][n2], 0, 0, 0);
    __builtin_amdgcn_s_setprio(0);

    // E: all waves done reading buf b -> safe to stage into it
    BAR_E();
    // F: stage A0,B0 of tile t+2 into buf b
    STAGE_A0(tn2); STAGE_B0(tn2);
    // G: tile t+1 fully staged (keep newest group in flight)
    WAIT_G();
  }
  asm volatile("s_waitcnt vmcnt(0)" ::: "memory");  // drain tail dup-stages

#undef STAGE_A0
#undef STAGE_A1
#undef STAGE_B0
#undef STAGE_B1

  // ---------------- epilogue ----------------
  const int bq = tt >> 2;               // batch
  const int tokb = (tt & 3) * 256;      // token offset within batch
  // q/k rowblocks: direct packed 8B stores (4 consecutive d per lane)
#pragma unroll
  for (int mi = 0; mi < 9; ++mi) {
    const int fblk = n0 + wr * 144 + mi * 16;   // 16-aligned; q/k/v boundary safe
    if (fblk < 1536) {
      const bool isq = fblk < 768;
      unsigned short* dst0 = isq ? qo : ko;
      const int fd = fblk - (isq ? 0 : 768);
      const int hh = fd >> 6;
      const int dih = (fd & 63) + lq * 4;
      f32x4 bias4 = {0.f, 0.f, 0.f, 0.f};
      if (isq) bias4 = *(const f32x4*)&qb[fblk + lq * 4];
#pragma unroll
      for (int ni = 0; ni < 4; ++ni) {
        const int tok = tokb + wc * 64 + ni * 16 + lm;
        uint2v pk;
        if (isq) {
          pk.x = pack2bf((acc[mi][ni][0] + bias4[0]) * QK_PRESCALE,
                         (acc[mi][ni][1] + bias4[1]) * QK_PRESCALE);
          pk.y = pack2bf((acc[mi][ni][2] + bias4[2]) * QK_PRESCALE,
                         (acc[mi][ni][3] + bias4[3]) * QK_PRESCALE);
        } else {
          pk.x = pack2bf(acc[mi][ni][0], acc[mi][ni][1]);
          pk.y = pack2bf(acc[mi][ni][2], acc[mi][ni][3]);
        }
        *(uint2v*)&dst0[(((size_t)(bq * 12 + hh)) * 1024 + tok) * 64 + dih] = pk;
      }
    }
  }
  // v rowblocks: transpose via LDS scratch (144 x stride 264), 2 passes
  if (n0 + 288 > 1536) {
#pragma unroll
    for (int p = 0; p < 2; ++p) {
      __syncthreads();
      if (wr == p) {
#pragma unroll
        for (int mi = 0; mi < 9; ++mi) {
          const int fblk = n0 + p * 144 + mi * 16;
          if (fblk >= 1536) {
            f32x4 bias4 = *(const f32x4*)&vb[fblk - 1536 + lq * 4];
#pragma unroll
            for (int ni = 0; ni < 4; ++ni) {
              const int tokl = wc * 64 + ni * 16 + lm;
#pragma unroll
              for (int r = 0; r < 4; ++r)
                lds[(mi * 16 + lq * 4 + r) * 264 + tokl] = f2bf(acc[mi][ni][r] + bias4[r]);
            }
          }
        }
      }
      __syncthreads();
      const int fv = 1536 - (n0 + p * 144);
      const int rv0 = fv > 0 ? fv : 0;
      for (int r = rv0 + (tid >> 2); r < 144; r += 128) {
        const int tq = tid & 3;
        const int dgv = n0 + p * 144 + r - 1536;      // 0..767
        const int hh = dgv >> 6, d = dgv & 63;
        unsigned short* dstv = vto + (((size_t)(bq * 12 + hh)) * 64 + d) * 1024 + tokb + tq * 64;
        const unsigned short* srcr = &lds[r * 264 + tq * 64];
#pragma unroll
        for (int j = 0; j < 8; ++j)
          *(uint4v*)&dstv[j * 8] = *(const uint4v*)&srcr[j * 8];
      }
    }
  }
}

// ---------------------------------------------------------------------------
// Flash attention. 768 blocks = 8 XCD x (12 bh x 8 q-tiles).
// R12: K/V double-buffered (async 1-deep prefetch, 1 barrier/tile), ps halved
// (PV per 32-key half) stride 40 + XOR(lm&8) conflict-free swizzle, mask
// hoisted.  LDS 46KB -> 3 blocks/CU.
// ---------------------------------------------------------------------------
__global__ __launch_bounds__(256, 3)
void attn_mfma(const unsigned short* __restrict__ q, const unsigned short* __restrict__ k,
               const unsigned short* __restrict__ vt, const int* __restrict__ mask,
               unsigned short* __restrict__ ao) {
  __shared__ unsigned short ks_s[2][64 * 64];  // dbuf K [key][hd], swizzled chunks
  __shared__ unsigned short vs_s[2][64 * 64];  // dbuf V [hd][key], swizzled chunks
  __shared__ unsigned short ps[4][32 * 40];    // per-wave P-half [q][32key], stride 40, XOR(lm&8)
  __shared__ float mkl[1024];                  // all mask bias, hoisted
  const int tid = threadIdx.x;
  const int lane = tid & 63, wid = tid >> 6;
  const int lm = lane & 15, lq = lane >> 4;
  const int xsw = lm & 7;
  const int sxor = (lm & 8) >> 1;              // 4 shorts (8B) if lm>=8
  const int L = blockIdx.x;
  const int xcd = L & 7, s = L >> 3;           // s: 0..95
  const int bh = xcd * 12 + s / 8;
  const int qt = s % 8;
  const int bb = bh / 12, hh = bh % 12;
  const unsigned short* qp = q + (size_t)bh * 65536;
  const unsigned short* kp = k + (size_t)bh * 65536;
  const unsigned short* vp = vt + (size_t)bh * 65536;
  const int* mp = mask + bb * 1024;
  const int q0 = qt * 128 + wid * 32;
  const int srow = lane >> 3;
  const int scolsw = ((lane & 7) ^ srow) * 8;
  const unsigned short* gk = kp + (size_t)(wid * 16 + srow) * 64 + scolsw;
  const unsigned short* gv = vp + (size_t)(wid * 16 + srow) * 1024 + scolsw;

#define STAGE_T(kt_, b_) { \
    gl_lds16(gk + (size_t)(kt_) * 4096, &ks_s[b_][(wid * 16) * 64]); \
    gl_lds16(gk + (size_t)(kt_) * 4096 + (size_t)8 * 64, &ks_s[b_][(wid * 16 + 8) * 64]); \
    gl_lds16(gv + (size_t)(kt_) * 64, &vs_s[b_][(wid * 16) * 64]); \
    gl_lds16(gv + (size_t)(kt_) * 64 + (size_t)8 * 1024, &vs_s[b_][(wid * 16 + 8) * 64]); }

  // hoisted mask -> mkl (int4 load, float4 store)
  {
    int4 mv = ((const int4*)mp)[tid];
    float4 f;
    f.x = mv.x ? -1e30f : 0.0f;
    f.y = mv.y ? -1e30f : 0.0f;
    f.z = mv.z ? -1e30f : 0.0f;
    f.w = mv.w ? -1e30f : 0.0f;
    ((float4*)mkl)[tid] = f;
  }

  bf16x8 qf[2][2];
#pragma unroll
  for (int mi = 0; mi < 2; ++mi)
#pragma unroll
    for (int ks2 = 0; ks2 < 2; ++ks2)
      qf[mi][ks2] = *(const bf16x8*)&qp[(size_t)(q0 + mi * 16 + lm) * 64 + ks2 * 32 + lq * 8];
  bf16x8 ones;
#pragma unroll
  for (int i = 0; i < 8; ++i) ones[i] = (__bf16)1.0f;

  f32x4 o_acc[2][4] = {};
  f32x4 l_acc[2] = {};

  // prologue: stage tile 0; __syncthreads drains vmcnt+lgkm (mkl + stage)
  STAGE_T(0, 0);
  __syncthreads();

  for (int kt = 0; kt < 16; ++kt) {
    const int b = kt & 1;
    if (kt) {
      // tile kt's stage (issued at kt-1) complete; all waves past tile kt-1
      asm volatile("s_waitcnt vmcnt(0)\ns_barrier" ::: "memory");
    }
    // async prefetch of tile kt+1 into the other buffer (covered by compute)
    if (kt < 15) STAGE_T(kt + 1, b ^ 1);

    // S^T = K Q^T : col=q=lm, row=key=lq*4+r (+16nt)
    f32x4 st[4][2] = {};
#pragma unroll
    for (int ks2 = 0; ks2 < 2; ++ks2) {
      bf16x8 kf[4];
#pragma unroll
      for (int nt = 0; nt < 4; ++nt)
        kf[nt] = *(const bf16x8*)&ks_s[b][(nt * 16 + lm) * 64 + (((ks2 * 4 + lq) ^ xsw) * 8)];
      __builtin_amdgcn_s_setprio(1);
#pragma unroll
      for (int nt = 0; nt < 4; ++nt)
#pragma unroll
        for (int mi = 0; mi < 2; ++mi)
          st[nt][mi] = __builtin_amdgcn_mfma_f32_16x16x32_bf16(kf[nt], qf[mi][ks2], st[nt][mi], 0, 0, 0);
      __builtin_amdgcn_s_setprio(0);
    }

    // two 32-key halves: softmax -> ps (swizzled) -> PV
#pragma unroll
    for (int h2 = 0; h2 < 2; ++h2) {
#pragma unroll
      for (int ntl = 0; ntl < 2; ++ntl) {
        const int nt = h2 * 2 + ntl;
        f32x4 mv4 = *(const f32x4*)&mkl[kt * 64 + nt * 16 + lq * 4];
#pragma unroll
        for (int mi = 0; mi < 2; ++mi) {
          uint2v pk;
          pk.x = pack2bf(__builtin_amdgcn_exp2f(st[nt][mi][0] + mv4[0]),
                         __builtin_amdgcn_exp2f(st[nt][mi][1] + mv4[1]));
          pk.y = pack2bf(__builtin_amdgcn_exp2f(st[nt][mi][2] + mv4[2]),
                         __builtin_amdgcn_exp2f(st[nt][mi][3] + mv4[3]));
          *(uint2v*)&ps[wid][(mi * 16 + lm) * 40 + ((ntl * 16 + lq * 4) ^ sxor)] = pk;
        }
      }
      // pf: 2x ds_read_b64 per mi (8B granule matches the XOR swizzle)
      bf16x8 pf[2], vf[4];
#pragma unroll
      for (int mi = 0; mi < 2; ++mi) {
        uint2v h0 = *(const uint2v*)&ps[wid][(mi * 16 + lm) * 40 + ((lq * 8) ^ sxor)];
        uint2v h1 = *(const uint2v*)&ps[wid][(mi * 16 + lm) * 40 + ((lq * 8 + 4) ^ sxor)];
        uint4v u; u.x = h0.x; u.y = h0.y; u.z = h1.x; u.w = h1.y;
        pf[mi] = __builtin_bit_cast(bf16x8, u);
      }
#pragma unroll
      for (int nt = 0; nt < 4; ++nt)
        vf[nt] = *(const bf16x8*)&vs_s[b][(nt * 16 + lm) * 64 + (((h2 * 4 + lq) ^ xsw) * 8)];
      __builtin_amdgcn_s_setprio(1);
#pragma unroll
      for (int mi = 0; mi < 2; ++mi) {
#pragma unroll
        for (int nt = 0; nt < 4; ++nt)
          o_acc[mi][nt] = __builtin_amdgcn_mfma_f32_16x16x32_bf16(pf[mi], vf[nt], o_acc[mi][nt], 0, 0, 0);
        l_acc[mi] = __builtin_amdgcn_mfma_f32_16x16x32_bf16(pf[mi], ones, l_acc[mi], 0, 0, 0);
      }
      __builtin_amdgcn_s_setprio(0);
    }
  }
#undef STAGE_T

  // epilogue: ao[b, tok, h*64+d] = O/l  (bf16)
#pragma unroll
  for (int mi = 0; mi < 2; ++mi) {
#pragma unroll
    for (int r = 0; r < 4; ++r) {
      float inv = 1.0f / l_acc[mi][r];
      int tok = q0 + mi * 16 + lq * 4 + r;
#pragma unroll
      for (int nt = 0; nt < 4; ++nt)
        ao[(size_t)(bb * 1024 + tok) * 768 + hh * 64 + nt * 16 + lm] = f2bf(o_acc[mi][nt][r] * inv);
    }
  }
}

// ---------------------------------------------------------------------------
// Proj GEMM: M=8192, N=768, K=768.  (unchanged)
// ---------------------------------------------------------------------------
__global__ __launch_bounds__(256)
void proj_gemm(const unsigned short* __restrict__ ab, const unsigned short* __restrict__ wb,
               const float* __restrict__ pb, float* __restrict__ out) {
  __shared__ unsigned short as[128 * 64];   // w rows
  __shared__ unsigned short bs[128 * 64];   // ao rows
  const int tid = threadIdx.x;
  const int lane = tid & 63, wid = tid >> 6;
  const int lm = lane & 15, lq = lane >> 4;
  const int xsw = lm & 7;
  const int wm = (wid & 1) * 64, wn = (wid >> 1) * 64;
  const int L = blockIdx.x;
  const int xcd = L & 7, s = L >> 3;           // s: 0..47
  const int m0 = (xcd * 8 + s / 6) * 128;
  const int n0 = (s % 6) * 128;
  const int srow = lane >> 3;
  const int scolsw = ((lane & 7) ^ srow) * 8;
  const unsigned short* ga = wb + (size_t)(n0 + wid * 32 + srow) * 768 + scolsw;
  const unsigned short* gb = ab + (size_t)(m0 + wid * 32 + srow) * 768 + scolsw;
  f32x4 acc[4][4] = {};
  for (int kt = 0; kt < 768; kt += 64) {
#pragma unroll
    for (int i = 0; i < 4; ++i) {
      gl_lds16(ga + kt + (size_t)i * 8 * 768, &as[(wid * 32 + i * 8) * 64]);
      gl_lds16(gb + kt + (size_t)i * 8 * 768, &bs[(wid * 32 + i * 8) * 64]);
    }
    __syncthreads();
#pragma unroll
    for (int ks = 0; ks < 2; ++ks) {
      bf16x8 af[4], bf[4];
#pragma unroll
      for (int i = 0; i < 4; ++i)
        af[i] = *(const bf16x8*)&as[(wm + i * 16 + lm) * 64 + (((ks * 4 + lq) ^ xsw) * 8)];
#pragma unroll
      for (int i = 0; i < 4; ++i)
        bf[i] = *(const bf16x8*)&bs[(wn + i * 16 + lm) * 64 + (((ks * 4 + lq) ^ xsw) * 8)];
#pragma unroll
      for (int mi = 0; mi < 4; ++mi)
#pragma unroll
        for (int ni = 0; ni < 4; ++ni)
          acc[mi][ni] = __builtin_amdgcn_mfma_f32_16x16x32_bf16(af[mi], bf[ni], acc[mi][ni], 0, 0, 0);
    }
    __syncthreads();
  }
  // acc rows = n-dim, cols = m-dim
#pragma unroll
  for (int mi = 0; mi < 4; ++mi) {
    int gn0 = n0 + wm + mi * 16 + lq * 4;
    f32x4 bias4 = *(const f32x4*)&pb[gn0];
#pragma unroll
    for (int ni = 0; ni < 4; ++ni) {
      int gm = m0 + wn + ni * 16 + lm;
      f32x4 o;
      o[0] = acc[mi][ni][0] + bias4[0];
      o[1] = acc[mi][ni][1] + bias4[1];
      o[2] = acc[mi][ni][2] + bias4[2];
      o[3] = acc[mi][ni][3] + bias4[3];
      *(f32x4*)&out[(size_t)gm * 768 + gn0] = o;
    }
  }
}

// ---------------------------------------------------------------------------
// ws layout (bf16 elts): xb 6291456 | wqkv 1769472 | wproj 589824 |
//   q 6291456 | k 6291456 | v^T 6291456 | ao 6291456   (~67.6 MB)
// ---------------------------------------------------------------------------
extern "C" void kernel_launch(void* const* d_in, const int* in_sizes, int n_in,
                              void* d_out, int out_size, void* d_ws, size_t ws_size,
                              hipStream_t stream) {
  const float* x      = (const float*)d_in[0];
  const int*   mask   = (const int*)d_in[1];
  const float* qkv_w  = (const float*)d_in[2];
  const float* q_bias = (const float*)d_in[3];
  const float* v_bias = (const float*)d_in[4];
  const float* proj_w = (const float*)d_in[5];
  const float* proj_b = (const float*)d_in[6];
  float* out = (float*)d_out;
  unsigned short* p = (unsigned short*)d_ws;
  unsigned short* xb     = p;              p += 6291456;
  unsigned short* wqkvb  = p;              p += 1769472;
  unsigned short* wprojb = p;              p += 589824;
  unsigned short* qo     = p;              p += 6291456;
  unsigned short* ko     = p;              p += 6291456;
  unsigned short* vto    = p;              p += 6291456;
  unsigned short* ao     = p;

  cvt3_kernel<<<8448, 256, 0, stream>>>(x, xb, qkv_w, wqkvb, proj_w, wprojb);
  qkv_gemm<<<256, 512, 0, stream>>>(xb, wqkvb, q_bias, v_bias, qo, ko, vto);
  attn_mfma<<<768, 256, 0, stream>>>(qo, ko, vto, mask, ao);
  proj_gemm<<<384, 256, 0, stream>>>(ao, wprojb, proj_b, out);
}